// Round 1
// baseline (1844.274 us; speedup 1.0000x reference)
//
#include <hip/hip_runtime.h>
#include <math.h>

#define NDOC 4
#define CCC  1024
#define DDD  768
#define HHH  12
#define EEE  42
#define MMM  8
#define PPP  1024
#define NBQ  12      // number of 64-blocks in 768
#define NK   99

// ---------------- K1: e_emb = logsumexp over valid mentions ----------------
__global__ __launch_bounds__(256) void k_eemb(const float* __restrict__ seq,
    const int* __restrict__ pos, const int* __restrict__ mask,
    float* __restrict__ eemb) {
  int e = blockIdx.x, doc = blockIdx.y;
  int base = (doc*EEE + e)*MMM;
  int p[MMM], mk[MMM];
#pragma unroll
  for (int m = 0; m < MMM; ++m) { p[m] = pos[base+m] + 1; mk[m] = mask[base+m]; }
  for (int d0 = threadIdx.x; d0 < DDD; d0 += 256) {
    float v[MMM]; float mx = -INFINITY;
#pragma unroll
    for (int m = 0; m < MMM; ++m) {
      v[m] = seq[(doc*CCC + p[m])*DDD + d0];
      if (mk[m]) mx = fmaxf(mx, v[m]);
    }
    float s = 0.f;
#pragma unroll
    for (int m = 0; m < MMM; ++m) if (mk[m]) s += expf(v[m]-mx);
    eemb[(doc*EEE + e)*DDD + d0] = logf(s) + mx;
  }
}

// ---------------- K2: e_att[doc][e][h][c] = masked mean of att rows --------
__global__ __launch_bounds__(256) void k_eatt(const float* __restrict__ att,
    const int* __restrict__ pos, const int* __restrict__ mask,
    float* __restrict__ eatt) {
  int head = blockIdx.x, e = blockIdx.y, doc = blockIdx.z;
  int base = (doc*EEE + e)*MMM;
  int j = threadIdx.x * 4;
  float ax=0.f, ay=0.f, az=0.f, aw=0.f; float cnt = 0.f;
#pragma unroll
  for (int m = 0; m < MMM; ++m) {
    int mk = mask[base+m];
    cnt += (float)mk;
    if (mk) {
      int pp = pos[base+m] + 1;
      const float4 a = *(const float4*)&att[((size_t)(doc*HHH + head)*CCC + pp)*CCC + j];
      ax += a.x; ay += a.y; az += a.z; aw += a.w;
    }
  }
  float inv = 1.f / cnt;
  float4 o; o.x = ax*inv; o.y = ay*inv; o.z = az*inv; o.w = aw*inv;
  *(float4*)&eatt[((size_t)((doc*EEE + e)*HHH + head))*CCC + j] = o;
}

// ---------------- K3: ht_att (product over heads, mean/12, row-normalize) --
__global__ __launch_bounds__(256) void k_htatt(const float* __restrict__ eatt,
    const int* __restrict__ hts, float* __restrict__ htatt) {
  int b = blockIdx.x; int doc = b >> 10; int r = b & 1023;
  int h0 = hts[(doc*PPP + r)*2 + 0];
  int t0 = hts[(doc*PPP + r)*2 + 1];
  const float* ea0 = &eatt[(size_t)((doc*EEE + h0)*HHH)*CCC];
  const float* ea1 = &eatt[(size_t)((doc*EEE + t0)*HHH)*CCC];
  int j = threadIdx.x * 4;
  float vx=0.f, vy=0.f, vz=0.f, vw=0.f;
#pragma unroll
  for (int hh = 0; hh < HHH; ++hh) {
    const float4 a  = *(const float4*)&ea0[hh*CCC + j];
    const float4 bq = *(const float4*)&ea1[hh*CCC + j];
    vx += a.x*bq.x; vy += a.y*bq.y; vz += a.z*bq.z; vw += a.w*bq.w;
  }
  const float inv12 = 1.f/12.f;
  vx *= inv12; vy *= inv12; vz *= inv12; vw *= inv12;
  float part = vx + vy + vz + vw;
  __shared__ float red[4];
  for (int off = 32; off > 0; off >>= 1) part += __shfl_down(part, off, 64);
  int lane = threadIdx.x & 63, wv = threadIdx.x >> 6;
  if (lane == 0) red[wv] = part;
  __syncthreads();
  if (threadIdx.x == 0) red[0] = red[0]+red[1]+red[2]+red[3];
  __syncthreads();
  float sc = 1.f / (red[0] + 1e-5f);
  float4 o; o.x = vx*sc; o.y = vy*sc; o.z = vz*sc; o.w = vw*sc;
  *(float4*)&htatt[((size_t)(doc*PPP + r))*CCC + j] = o;
}

// ---------------- K4: rs[doc] = ht_att[doc] @ seq[doc]  (fp32 tiled) -------
__global__ __launch_bounds__(256) void k_rs(const float* __restrict__ A,
    const float* __restrict__ B, float* __restrict__ Cm) {
  __shared__ float AsT[32][68];
  __shared__ float Bs[32][68];
  int doc = blockIdx.z;
  int r0 = blockIdx.y * 64, c0 = blockIdx.x * 64;
  const float* Ad = A + (size_t)doc*CCC*CCC;
  const float* Bd = B + (size_t)doc*CCC*DDD;
  int t = threadIdx.x;
  int tx = t & 15, ty = t >> 4;
  float acc[4][4] = {};
  for (int k0 = 0; k0 < CCC; k0 += 32) {
    {
      int arow = t >> 3; int ak4 = (t & 7)*4;
#pragma unroll
      for (int rep = 0; rep < 2; ++rep) {
        int rr = arow + rep*32;
        const float4 a = *(const float4*)&Ad[(r0 + rr)*CCC + k0 + ak4];
        AsT[ak4+0][rr] = a.x; AsT[ak4+1][rr] = a.y; AsT[ak4+2][rr] = a.z; AsT[ak4+3][rr] = a.w;
      }
      int bk = t >> 3; int bn8 = (t & 7)*8;
      const float4 b0 = *(const float4*)&Bd[(k0 + bk)*DDD + c0 + bn8];
      const float4 b1 = *(const float4*)&Bd[(k0 + bk)*DDD + c0 + bn8 + 4];
      *(float4*)&Bs[bk][bn8]   = b0;
      *(float4*)&Bs[bk][bn8+4] = b1;
    }
    __syncthreads();
#pragma unroll
    for (int k = 0; k < 32; ++k) {
      const float4 a4 = *(const float4*)&AsT[k][ty*4];
      const float4 b4 = *(const float4*)&Bs[k][tx*4];
      float av[4] = {a4.x,a4.y,a4.z,a4.w};
      float bv[4] = {b4.x,b4.y,b4.z,b4.w};
#pragma unroll
      for (int i = 0; i < 4; ++i)
#pragma unroll
        for (int j = 0; j < 4; ++j)
          acc[i][j] += av[i]*bv[j];
    }
    __syncthreads();
  }
  float* Cd = Cm + (size_t)doc*CCC*DDD;
#pragma unroll
  for (int i = 0; i < 4; ++i) {
    float4 o; o.x=acc[i][0]; o.y=acc[i][1]; o.z=acc[i][2]; o.w=acc[i][3];
    *(float4*)&Cd[(r0 + ty*4 + i)*DDD + c0 + tx*4] = o;
  }
}

// ------- K5: out = tanh([gather(e_emb)|rs] @ W^T + b)  (fp32 tiled) --------
__global__ __launch_bounds__(256) void k_head(const float* __restrict__ eemb,
    const float* __restrict__ rs, const int* __restrict__ hts,
    const float* __restrict__ W, const float* __restrict__ bias,
    float* __restrict__ out, int which) {
  __shared__ float AsT[32][68];
  __shared__ float Bs[32][68];
  int r0 = blockIdx.y * 64;
  int c0 = blockIdx.x * 64;
  int doc = r0 >> 10;
  int t = threadIdx.x;
  int tx = t & 15, ty = t >> 4;
  float acc[4][4] = {};
  for (int k0 = 0; k0 < 2*DDD; k0 += 32) {
    {
      int arow = t >> 3; int ak4 = (t & 7)*4; int k = k0 + ak4;
#pragma unroll
      for (int rep = 0; rep < 2; ++rep) {
        int rr = arow + rep*32;
        int rrr = (r0 + rr) & 1023;
        const float* src;
        if (k < DDD) {
          int idx = hts[(doc*PPP + rrr)*2 + which];
          src = &eemb[(doc*EEE + idx)*DDD + k];
        } else {
          src = &rs[((size_t)(doc*PPP + rrr))*DDD + (k - DDD)];
        }
        const float4 a = *(const float4*)src;
        AsT[ak4+0][rr] = a.x; AsT[ak4+1][rr] = a.y; AsT[ak4+2][rr] = a.z; AsT[ak4+3][rr] = a.w;
      }
      int col = t >> 3; int kk4 = (t & 7)*4;
#pragma unroll
      for (int rep = 0; rep < 2; ++rep) {
        int cc = col + rep*32;
        const float4 w4 = *(const float4*)&W[(size_t)(c0 + cc)*(2*DDD) + k0 + kk4];
        Bs[kk4+0][cc] = w4.x; Bs[kk4+1][cc] = w4.y; Bs[kk4+2][cc] = w4.z; Bs[kk4+3][cc] = w4.w;
      }
    }
    __syncthreads();
#pragma unroll
    for (int k = 0; k < 32; ++k) {
      const float4 a4 = *(const float4*)&AsT[k][ty*4];
      const float4 b4 = *(const float4*)&Bs[k][tx*4];
      float av[4] = {a4.x,a4.y,a4.z,a4.w};
      float bv[4] = {b4.x,b4.y,b4.z,b4.w};
#pragma unroll
      for (int i = 0; i < 4; ++i)
#pragma unroll
        for (int j = 0; j < 4; ++j)
          acc[i][j] += av[i]*bv[j];
    }
    __syncthreads();
  }
#pragma unroll
  for (int i = 0; i < 4; ++i) {
    int grow = r0 + ty*4 + i;
    float4 o;
    o.x = tanhf(acc[i][0] + bias[c0+tx*4+0]);
    o.y = tanhf(acc[i][1] + bias[c0+tx*4+1]);
    o.z = tanhf(acc[i][2] + bias[c0+tx*4+2]);
    o.w = tanhf(acc[i][3] + bias[c0+tx*4+3]);
    *(float4*)&out[(size_t)grow*DDD + c0 + tx*4] = o;
  }
}

// ------- K6: fused grouped-bilinear logits (never materialize bl) ---------
// logits[r,k] = sum_nb sum_i sum_j hs[r,nb*64+i] * Wb[k, nb*4096+i*64+j] * ts[r,nb*64+j]
__global__ __launch_bounds__(256) void k_logits(const float* __restrict__ hsb,
    const float* __restrict__ tsb, const float* __restrict__ Wb,
    float* __restrict__ logits) {
  __shared__ float hsT[64][68];   // [i][r]
  __shared__ float tsl[64][68];   // [r][j]
  __shared__ float wbl[64][68];   // [i][j]
  int kg = blockIdx.x;            // k0 = kg*9, 11*9 = 99
  int r0 = blockIdx.y * 64;
  int t = threadIdx.x;
  int jg = t & 7, ib = (t >> 3) & 1, rg = t >> 4;
  float acc[9][4] = {};
  for (int nb = 0; nb < NBQ; ++nb) {
    __syncthreads();  // previous iter's hsT/tsl reads done
    {
      int rr = t >> 4;          // 0..15
      int i4 = (t & 15) * 4;    // 0..60
#pragma unroll
      for (int rep = 0; rep < 4; ++rep) {
        int r = rr + rep*16;
        const float4 hv = *(const float4*)&hsb[(size_t)(r0 + r)*DDD + nb*64 + i4];
        hsT[i4+0][r] = hv.x; hsT[i4+1][r] = hv.y; hsT[i4+2][r] = hv.z; hsT[i4+3][r] = hv.w;
        const float4 tv = *(const float4*)&tsb[(size_t)(r0 + r)*DDD + nb*64 + i4];
        *(float4*)&tsl[r][i4] = tv;
      }
    }
#pragma unroll
    for (int kk = 0; kk < 9; ++kk) {
      __syncthreads();  // hsT/tsl staged (kk=0) / previous wbl reads done
      {
        const float* wsrc = &Wb[(size_t)(kg*9 + kk)*(NBQ*4096) + nb*4096];
#pragma unroll
        for (int rep = 0; rep < 4; ++rep) {
          int flat = t*4 + rep*1024;
          int wi = flat >> 6, wj = flat & 63;
          *(float4*)&wbl[wi][wj] = *(const float4*)&wsrc[flat];
        }
      }
      __syncthreads();
      float s0[4][4] = {}, s1[4][4] = {};
      const int ibase = ib*32;
#pragma unroll 4
      for (int ii = 0; ii < 32; ++ii) {
        int i = ibase + ii;
        const float4 h4 = *(const float4*)&hsT[i][rg*4];
        const float4 w0 = *(const float4*)&wbl[i][jg*4];
        const float4 w1 = *(const float4*)&wbl[i][jg*4 + 32];
        float hv[4] = {h4.x,h4.y,h4.z,h4.w};
        float w0v[4] = {w0.x,w0.y,w0.z,w0.w};
        float w1v[4] = {w1.x,w1.y,w1.z,w1.w};
#pragma unroll
        for (int rr = 0; rr < 4; ++rr)
#pragma unroll
          for (int jj = 0; jj < 4; ++jj) {
            s0[rr][jj] += hv[rr]*w0v[jj];
            s1[rr][jj] += hv[rr]*w1v[jj];
          }
      }
#pragma unroll
      for (int rr = 0; rr < 4; ++rr) {
        const float4 t0 = *(const float4*)&tsl[rg*4+rr][jg*4];
        const float4 t1 = *(const float4*)&tsl[rg*4+rr][jg*4+32];
        acc[kk][rr] += s0[rr][0]*t0.x + s0[rr][1]*t0.y + s0[rr][2]*t0.z + s0[rr][3]*t0.w
                     + s1[rr][0]*t1.x + s1[rr][1]*t1.y + s1[rr][2]*t1.z + s1[rr][3]*t1.w;
      }
    }
  }
  // reduce partials over the 16-lane (jg, ib) group
#pragma unroll
  for (int kk = 0; kk < 9; ++kk)
#pragma unroll
    for (int rr = 0; rr < 4; ++rr) {
      float v = acc[kk][rr];
      v += __shfl_xor(v, 1, 64);
      v += __shfl_xor(v, 2, 64);
      v += __shfl_xor(v, 4, 64);
      v += __shfl_xor(v, 8, 64);
      acc[kk][rr] = v;
    }
  if ((t & 15) == 0) {
#pragma unroll
    for (int kk = 0; kk < 9; ++kk)
#pragma unroll
      for (int rr = 0; rr < 4; ++rr)
        logits[(size_t)(r0 + rg*4 + rr)*NK + kg*9 + kk] = acc[kk][rr];
  }
}

extern "C" void kernel_launch(void* const* d_in, const int* in_sizes, int n_in,
                              void* d_out, int out_size, void* d_ws, size_t ws_size,
                              hipStream_t stream) {
  const float* seq  = (const float*)d_in[0];
  const float* att  = (const float*)d_in[1];
  const float* Wh   = (const float*)d_in[2];
  const float* bh   = (const float*)d_in[3];
  const float* Wt   = (const float*)d_in[4];
  const float* bt   = (const float*)d_in[5];
  const float* Wb   = (const float*)d_in[6];
  const int* pos    = (const int*)d_in[7];
  const int* mask   = (const int*)d_in[8];
  const int* hts    = (const int*)d_in[9];
  float* out = (float*)d_out;

  float* ws   = (float*)d_ws;
  float* eatt = ws;                   // 4*42*12*1024 = 2,064,384
  float* htat = eatt + 2064384;       // 4*1024*1024  = 4,194,304
  float* eemb = htat + 4194304;       // 4*42*768     = 129,024
  float* rs   = eemb + 129024;        // 4*1024*768   = 3,145,728
  float* hsb  = rs   + 3145728;       // 4096*768
  float* tsb  = hsb  + 3145728;       // 4096*768

  k_eemb<<<dim3(EEE, NDOC), 256, 0, stream>>>(seq, pos, mask, eemb);
  k_eatt<<<dim3(HHH, EEE, NDOC), 256, 0, stream>>>(att, pos, mask, eatt);
  k_htatt<<<dim3(NDOC*PPP), 256, 0, stream>>>(eatt, hts, htat);
  k_rs<<<dim3(DDD/64, CCC/64, NDOC), 256, 0, stream>>>(htat, seq, rs);
  k_head<<<dim3(DDD/64, (NDOC*PPP)/64), 256, 0, stream>>>(eemb, rs, hts, Wh, bh, hsb, 0);
  k_head<<<dim3(DDD/64, (NDOC*PPP)/64), 256, 0, stream>>>(eemb, rs, hts, Wt, bt, tsb, 1);
  k_logits<<<dim3(11, (NDOC*PPP)/64), 256, 0, stream>>>(hsb, tsb, Wb, out);
}

// Round 2
// 608.314 us; speedup vs baseline: 3.0318x; 3.0318x over previous
//
#include <hip/hip_runtime.h>
#include <hip/hip_bf16.h>
#include <math.h>

#define NDOC 4
#define CCC  1024
#define DDD  768
#define HHH  12
#define EEE  42
#define MMM  8
#define PPP  1024
#define NBQ  12      // number of 64-blocks in 768
#define NK   99
#define NPAD 112     // 99 padded to 7 n-tiles of 16

typedef __attribute__((ext_vector_type(8))) short short8v;
typedef __attribute__((ext_vector_type(4))) float floatx4;

__device__ __forceinline__ float bf16_to_f32(unsigned short u) {
  return __builtin_bit_cast(float, ((unsigned int)u) << 16);
}
__device__ __forceinline__ short f32_to_bf16s(float f) {
  return __builtin_bit_cast(short, __float2bfloat16(f));
}

// ---------------- K1: e_emb = logsumexp over valid mentions ----------------
__global__ __launch_bounds__(256) void k_eemb(const float* __restrict__ seq,
    const int* __restrict__ pos, const int* __restrict__ mask,
    float* __restrict__ eemb) {
  int e = blockIdx.x, doc = blockIdx.y;
  int base = (doc*EEE + e)*MMM;
  int p[MMM], mk[MMM];
#pragma unroll
  for (int m = 0; m < MMM; ++m) { p[m] = pos[base+m] + 1; mk[m] = mask[base+m]; }
  for (int d0 = threadIdx.x; d0 < DDD; d0 += 256) {
    float v[MMM]; float mx = -INFINITY;
#pragma unroll
    for (int m = 0; m < MMM; ++m) {
      v[m] = seq[(doc*CCC + p[m])*DDD + d0];
      if (mk[m]) mx = fmaxf(mx, v[m]);
    }
    float s = 0.f;
#pragma unroll
    for (int m = 0; m < MMM; ++m) if (mk[m]) s += expf(v[m]-mx);
    eemb[(doc*EEE + e)*DDD + d0] = logf(s) + mx;
  }
}

// ---------------- K2: e_att[doc][e][h][c] = masked mean of att rows --------
__global__ __launch_bounds__(256) void k_eatt(const float* __restrict__ att,
    const int* __restrict__ pos, const int* __restrict__ mask,
    float* __restrict__ eatt) {
  int head = blockIdx.x, e = blockIdx.y, doc = blockIdx.z;
  int base = (doc*EEE + e)*MMM;
  int j = threadIdx.x * 4;
  float ax=0.f, ay=0.f, az=0.f, aw=0.f; float cnt = 0.f;
#pragma unroll
  for (int m = 0; m < MMM; ++m) {
    int mk = mask[base+m];
    cnt += (float)mk;
    if (mk) {
      int pp = pos[base+m] + 1;
      const float4 a = *(const float4*)&att[((size_t)(doc*HHH + head)*CCC + pp)*CCC + j];
      ax += a.x; ay += a.y; az += a.z; aw += a.w;
    }
  }
  float inv = 1.f / cnt;
  float4 o; o.x = ax*inv; o.y = ay*inv; o.z = az*inv; o.w = aw*inv;
  *(float4*)&eatt[((size_t)((doc*EEE + e)*HHH + head))*CCC + j] = o;
}

// ---------------- K3: ht_att (product over heads, mean/12, row-normalize) --
__global__ __launch_bounds__(256) void k_htatt(const float* __restrict__ eatt,
    const int* __restrict__ hts, float* __restrict__ htatt) {
  int b = blockIdx.x; int doc = b >> 10; int r = b & 1023;
  int h0 = hts[(doc*PPP + r)*2 + 0];
  int t0 = hts[(doc*PPP + r)*2 + 1];
  const float* ea0 = &eatt[(size_t)((doc*EEE + h0)*HHH)*CCC];
  const float* ea1 = &eatt[(size_t)((doc*EEE + t0)*HHH)*CCC];
  int j = threadIdx.x * 4;
  float vx=0.f, vy=0.f, vz=0.f, vw=0.f;
#pragma unroll
  for (int hh = 0; hh < HHH; ++hh) {
    const float4 a  = *(const float4*)&ea0[hh*CCC + j];
    const float4 bq = *(const float4*)&ea1[hh*CCC + j];
    vx += a.x*bq.x; vy += a.y*bq.y; vz += a.z*bq.z; vw += a.w*bq.w;
  }
  const float inv12 = 1.f/12.f;
  vx *= inv12; vy *= inv12; vz *= inv12; vw *= inv12;
  float part = vx + vy + vz + vw;
  __shared__ float red[4];
  for (int off = 32; off > 0; off >>= 1) part += __shfl_down(part, off, 64);
  int lane = threadIdx.x & 63, wv = threadIdx.x >> 6;
  if (lane == 0) red[wv] = part;
  __syncthreads();
  if (threadIdx.x == 0) red[0] = red[0]+red[1]+red[2]+red[3];
  __syncthreads();
  float sc = 1.f / (red[0] + 1e-5f);
  float4 o; o.x = vx*sc; o.y = vy*sc; o.z = vz*sc; o.w = vw*sc;
  *(float4*)&htatt[((size_t)(doc*PPP + r))*CCC + j] = o;
}

// ---------------- K4: rs[doc] = ht_att[doc] @ seq[doc]  (fp32 tiled) -------
__global__ __launch_bounds__(256) void k_rs(const float* __restrict__ A,
    const float* __restrict__ B, float* __restrict__ Cm) {
  __shared__ float AsT[32][68];
  __shared__ float Bs[32][68];
  int doc = blockIdx.z;
  int r0 = blockIdx.y * 64, c0 = blockIdx.x * 64;
  const float* Ad = A + (size_t)doc*CCC*CCC;
  const float* Bd = B + (size_t)doc*CCC*DDD;
  int t = threadIdx.x;
  int tx = t & 15, ty = t >> 4;
  float acc[4][4] = {};
  for (int k0 = 0; k0 < CCC; k0 += 32) {
    {
      int arow = t >> 3; int ak4 = (t & 7)*4;
#pragma unroll
      for (int rep = 0; rep < 2; ++rep) {
        int rr = arow + rep*32;
        const float4 a = *(const float4*)&Ad[(r0 + rr)*CCC + k0 + ak4];
        AsT[ak4+0][rr] = a.x; AsT[ak4+1][rr] = a.y; AsT[ak4+2][rr] = a.z; AsT[ak4+3][rr] = a.w;
      }
      int bk = t >> 3; int bn8 = (t & 7)*8;
      const float4 b0 = *(const float4*)&Bd[(k0 + bk)*DDD + c0 + bn8];
      const float4 b1 = *(const float4*)&Bd[(k0 + bk)*DDD + c0 + bn8 + 4];
      *(float4*)&Bs[bk][bn8]   = b0;
      *(float4*)&Bs[bk][bn8+4] = b1;
    }
    __syncthreads();
#pragma unroll
    for (int k = 0; k < 32; ++k) {
      const float4 a4 = *(const float4*)&AsT[k][ty*4];
      const float4 b4 = *(const float4*)&Bs[k][tx*4];
      float av[4] = {a4.x,a4.y,a4.z,a4.w};
      float bv[4] = {b4.x,b4.y,b4.z,b4.w};
#pragma unroll
      for (int i = 0; i < 4; ++i)
#pragma unroll
        for (int j = 0; j < 4; ++j)
          acc[i][j] += av[i]*bv[j];
    }
    __syncthreads();
  }
  float* Cd = Cm + (size_t)doc*CCC*DDD;
#pragma unroll
  for (int i = 0; i < 4; ++i) {
    float4 o; o.x=acc[i][0]; o.y=acc[i][1]; o.z=acc[i][2]; o.w=acc[i][3];
    *(float4*)&Cd[(r0 + ty*4 + i)*DDD + c0 + tx*4] = o;
  }
}

// ------- K5: out = tanh([gather(e_emb)|rs] @ W^T + b)  (fp32 tiled) --------
__global__ __launch_bounds__(256) void k_head(const float* __restrict__ eemb,
    const float* __restrict__ rs, const int* __restrict__ hts,
    const float* __restrict__ W, const float* __restrict__ bias,
    float* __restrict__ out, int which) {
  __shared__ float AsT[32][68];
  __shared__ float Bs[32][68];
  int r0 = blockIdx.y * 64;
  int c0 = blockIdx.x * 64;
  int doc = r0 >> 10;
  int t = threadIdx.x;
  int tx = t & 15, ty = t >> 4;
  float acc[4][4] = {};
  for (int k0 = 0; k0 < 2*DDD; k0 += 32) {
    {
      int arow = t >> 3; int ak4 = (t & 7)*4; int k = k0 + ak4;
#pragma unroll
      for (int rep = 0; rep < 2; ++rep) {
        int rr = arow + rep*32;
        int rrr = (r0 + rr) & 1023;
        const float* src;
        if (k < DDD) {
          int idx = hts[(doc*PPP + rrr)*2 + which];
          src = &eemb[(doc*EEE + idx)*DDD + k];
        } else {
          src = &rs[((size_t)(doc*PPP + rrr))*DDD + (k - DDD)];
        }
        const float4 a = *(const float4*)src;
        AsT[ak4+0][rr] = a.x; AsT[ak4+1][rr] = a.y; AsT[ak4+2][rr] = a.z; AsT[ak4+3][rr] = a.w;
      }
      int col = t >> 3; int kk4 = (t & 7)*4;
#pragma unroll
      for (int rep = 0; rep < 2; ++rep) {
        int cc = col + rep*32;
        const float4 w4 = *(const float4*)&W[(size_t)(c0 + cc)*(2*DDD) + k0 + kk4];
        Bs[kk4+0][cc] = w4.x; Bs[kk4+1][cc] = w4.y; Bs[kk4+2][cc] = w4.z; Bs[kk4+3][cc] = w4.w;
      }
    }
    __syncthreads();
#pragma unroll
    for (int k = 0; k < 32; ++k) {
      const float4 a4 = *(const float4*)&AsT[k][ty*4];
      const float4 b4 = *(const float4*)&Bs[k][tx*4];
      float av[4] = {a4.x,a4.y,a4.z,a4.w};
      float bv[4] = {b4.x,b4.y,b4.z,b4.w};
#pragma unroll
      for (int i = 0; i < 4; ++i)
#pragma unroll
        for (int j = 0; j < 4; ++j)
          acc[i][j] += av[i]*bv[j];
    }
    __syncthreads();
  }
#pragma unroll
  for (int i = 0; i < 4; ++i) {
    int grow = r0 + ty*4 + i;
    float4 o;
    o.x = tanhf(acc[i][0] + bias[c0+tx*4+0]);
    o.y = tanhf(acc[i][1] + bias[c0+tx*4+1]);
    o.z = tanhf(acc[i][2] + bias[c0+tx*4+2]);
    o.w = tanhf(acc[i][3] + bias[c0+tx*4+3]);
    *(float4*)&out[(size_t)grow*DDD + c0 + tx*4] = o;
  }
}

// ------- K6a: pack Wb fp32 [99][49152] -> bf16 tiles Wp[ki][n(112)][j(64)] --
// ki = nb*64 + i, flat out elem o = ki*7168 + n*64 + j ; n>=99 zero-filled.
__global__ __launch_bounds__(256) void k_prep_w(const float* __restrict__ Wb,
    unsigned short* __restrict__ Wp) {
  int t = blockIdx.x*256 + threadIdx.x;      // one thread per 16B out chunk
  int j = (t & 7) * 8;
  int n = (t >> 3) % NPAD;
  int ki = t / 896;                           // 896 = 112*8 chunks per ki
  unsigned short o[8];
  if (n < NK) {
    const float* src = &Wb[(size_t)n*49152 + ki*64 + j];
    float4 v0 = *(const float4*)src;
    float4 v1 = *(const float4*)(src+4);
    o[0]=__builtin_bit_cast(unsigned short,__float2bfloat16(v0.x));
    o[1]=__builtin_bit_cast(unsigned short,__float2bfloat16(v0.y));
    o[2]=__builtin_bit_cast(unsigned short,__float2bfloat16(v0.z));
    o[3]=__builtin_bit_cast(unsigned short,__float2bfloat16(v0.w));
    o[4]=__builtin_bit_cast(unsigned short,__float2bfloat16(v1.x));
    o[5]=__builtin_bit_cast(unsigned short,__float2bfloat16(v1.y));
    o[6]=__builtin_bit_cast(unsigned short,__float2bfloat16(v1.z));
    o[7]=__builtin_bit_cast(unsigned short,__float2bfloat16(v1.w));
  } else {
#pragma unroll
    for (int e=0;e<8;++e) o[e]=0;
  }
  *(uint4*)&Wp[(size_t)ki*7168 + n*64 + j] = *(const uint4*)o;
}

// ------- K6b: hsT_g[i][r] = bf16(hs[r][i])  (transpose via LDS) ------------
__global__ __launch_bounds__(256) void k_pack_hs(const float* __restrict__ hs,
    unsigned short* __restrict__ hsT) {
  __shared__ float tl[64][65];
  int i0 = blockIdx.x * 64, r0 = blockIdx.y * 64;
  int t = threadIdx.x;
#pragma unroll
  for (int rep = 0; rep < 4; ++rep) {
    int r = rep*16 + (t >> 4);
    int c4 = (t & 15) * 4;
    float4 v = *(const float4*)&hs[(size_t)(r0 + r)*DDD + i0 + c4];
    tl[r][c4+0]=v.x; tl[r][c4+1]=v.y; tl[r][c4+2]=v.z; tl[r][c4+3]=v.w;
  }
  __syncthreads();
#pragma unroll
  for (int rep = 0; rep < 4; ++rep) {
    int i = rep*16 + (t >> 4);
    int r4 = (t & 15) * 4;
    unsigned short o[4];
#pragma unroll
    for (int kq = 0; kq < 4; ++kq)
      o[kq] = __builtin_bit_cast(unsigned short, __float2bfloat16(tl[r4+kq][i]));
    *(uint2*)&hsT[(size_t)(i0 + i)*4096 + r0 + r4] = *(const uint2*)o;
  }
}

// ------- K6c: zero logits (needed: atomicAdd accumulation + graph replays) -
__global__ __launch_bounds__(256) void k_zero(float* __restrict__ p) {
  int t = blockIdx.x*256 + threadIdx.x;
  float4 z; z.x=z.y=z.z=z.w=0.f;
  *(float4*)&p[(size_t)t*4] = z;
}

// ------- K6: logits via bf16 MFMA, A = outer(hs,ts) generated on the fly ---
// grid (24, 32): x = nb*2 + ihalf, y = mtile(128 rows). 128 threads (2 waves).
// logits[r][k] += sum over flat K-chunk of  hs[r,i]*ts[r,j] * Wb[k, nb,i,j]
__global__ __launch_bounds__(128, 2) void k_logits_mfma(
    const unsigned short* __restrict__ hsT,   // [768][4096] bf16
    const float* __restrict__ tsb,            // [4096][768] fp32
    const unsigned short* __restrict__ Wp,    // [768 ki][112 n][64 j] bf16
    float* __restrict__ logits) {
  __shared__ unsigned short hsT_l[32*128];    // [ii][r] 8KB
  __shared__ unsigned short Bt_l[NPAD*72];    // [n][j] pad 72, 16.1KB
  const int nb = blockIdx.x >> 1;
  const int ih = (blockIdx.x & 1) * 32;
  const int mtile = blockIdx.y;
  const int t = threadIdx.x;
  const int w = t >> 6;          // wave 0/1
  const int lane = t & 63;
  const int ln = lane & 15;
  const int q = lane >> 4;
  const int m0w = mtile*128 + w*64;

  // stage hsT tile: rows (nb*64+ih ..+32) x cols (mtile*128 ..+128)
#pragma unroll
  for (int rep = 0; rep < 4; ++rep) {
    int c16 = t + rep*128;             // 512 chunks of 16B
    int ii = c16 >> 4;
    int c8 = (c16 & 15) * 8;
    uint4 v = *(const uint4*)&hsT[(size_t)(nb*64 + ih + ii)*4096 + mtile*128 + c8];
    *(uint4*)&hsT_l[ii*128 + c8] = v;
  }

  // ts values for this lane's A-fragment rows, held in registers (fp32)
  float tsr[4][2][8];
#pragma unroll
  for (int rt = 0; rt < 4; ++rt) {
    int row = m0w + rt*16 + ln;
#pragma unroll
    for (int js = 0; js < 2; ++js) {
      const float* p = &tsb[(size_t)row*DDD + nb*64 + js*32 + q*8];
      float4 v0 = *(const float4*)p;
      float4 v1 = *(const float4*)(p+4);
      tsr[rt][js][0]=v0.x; tsr[rt][js][1]=v0.y; tsr[rt][js][2]=v0.z; tsr[rt][js][3]=v0.w;
      tsr[rt][js][4]=v1.x; tsr[rt][js][5]=v1.y; tsr[rt][js][6]=v1.z; tsr[rt][js][7]=v1.w;
    }
  }

  floatx4 acc[4][7];
#pragma unroll
  for (int rt = 0; rt < 4; ++rt)
#pragma unroll
    for (int nt = 0; nt < 7; ++nt)
      acc[rt][nt] = (floatx4){0.f,0.f,0.f,0.f};

  for (int ii = 0; ii < 32; ++ii) {
    const int ki = nb*64 + ih + ii;
    // issue B-tile global loads (uint4 = 8 bf16) before barrier for overlap
    uint4 wreg[7];
#pragma unroll
    for (int r = 0; r < 7; ++r) {
      int chunk = t + r*128;           // 896 chunks
      wreg[r] = *(const uint4*)&Wp[(size_t)ki*7168 + chunk*8];
    }
    __syncthreads();                    // everyone done reading prev B tile
#pragma unroll
    for (int r = 0; r < 7; ++r) {
      int chunk = t + r*128;
      int n = chunk >> 3, j8 = (chunk & 7)*8;
      *(uint4*)&Bt_l[n*72 + j8] = wreg[r];
    }
    __syncthreads();

    float h[4];
#pragma unroll
    for (int rt = 0; rt < 4; ++rt)
      h[rt] = bf16_to_f32(hsT_l[ii*128 + w*64 + rt*16 + ln]);

#pragma unroll
    for (int js = 0; js < 2; ++js) {
      short8v a[4];
#pragma unroll
      for (int rt = 0; rt < 4; ++rt) {
#pragma unroll
        for (int e = 0; e < 8; ++e)
          a[rt][e] = f32_to_bf16s(h[rt] * tsr[rt][js][e]);
      }
      short8v b[7];
#pragma unroll
      for (int nt = 0; nt < 7; ++nt)
        b[nt] = *(const short8v*)&Bt_l[(nt*16 + ln)*72 + js*32 + q*8];
#pragma unroll
      for (int rt = 0; rt < 4; ++rt)
#pragma unroll
        for (int nt = 0; nt < 7; ++nt)
          acc[rt][nt] = __builtin_amdgcn_mfma_f32_16x16x32_bf16(a[rt], b[nt], acc[rt][nt], 0, 0, 0);
    }
  }

  // epilogue: C/D layout col=lane&15, row=(lane>>4)*4+reg  (m89-verified)
#pragma unroll
  for (int nt = 0; nt < 7; ++nt) {
    int col = nt*16 + ln;
    if (col < NK) {
#pragma unroll
      for (int rt = 0; rt < 4; ++rt) {
#pragma unroll
        for (int reg = 0; reg < 4; ++reg) {
          int row = m0w + rt*16 + q*4 + reg;
          atomicAdd(&logits[(size_t)row*NK + col], acc[rt][nt][reg]);
        }
      }
    }
  }
}

extern "C" void kernel_launch(void* const* d_in, const int* in_sizes, int n_in,
                              void* d_out, int out_size, void* d_ws, size_t ws_size,
                              hipStream_t stream) {
  const float* seq  = (const float*)d_in[0];
  const float* att  = (const float*)d_in[1];
  const float* Wh   = (const float*)d_in[2];
  const float* bh   = (const float*)d_in[3];
  const float* Wt   = (const float*)d_in[4];
  const float* bt   = (const float*)d_in[5];
  const float* Wb   = (const float*)d_in[6];
  const int* pos    = (const int*)d_in[7];
  const int* mask   = (const int*)d_in[8];
  const int* hts    = (const int*)d_in[9];
  float* out = (float*)d_out;

  float* ws   = (float*)d_ws;
  float* eatt = ws;                   // 4*42*12*1024 = 2,064,384 floats
  float* htat = eatt + 2064384;       // 4*1024*1024  = 4,194,304
  float* eemb = htat + 4194304;       // 4*42*768     = 129,024
  float* rs   = eemb + 129024;        // 4*1024*768   = 3,145,728
  float* hsb  = rs   + 3145728;       // 4096*768
  float* tsb  = hsb  + 3145728;       // 4096*768
  // aliased scratch (regions free by the time these are written):
  unsigned short* Wp_g  = (unsigned short*)eatt; // 5.5M ushort <= eatt+htat (25MB)
  unsigned short* hsT_g = (unsigned short*)rs;   // 3.1M ushort <= rs (12.6MB)

  k_eemb<<<dim3(EEE, NDOC), 256, 0, stream>>>(seq, pos, mask, eemb);
  k_eatt<<<dim3(HHH, EEE, NDOC), 256, 0, stream>>>(att, pos, mask, eatt);
  k_htatt<<<dim3(NDOC*PPP), 256, 0, stream>>>(eatt, hts, htat);
  k_rs<<<dim3(DDD/64, CCC/64, NDOC), 256, 0, stream>>>(htat, seq, rs);
  k_head<<<dim3(DDD/64, (NDOC*PPP)/64), 256, 0, stream>>>(eemb, rs, hts, Wh, bh, hsb, 0);
  k_head<<<dim3(DDD/64, (NDOC*PPP)/64), 256, 0, stream>>>(eemb, rs, hts, Wt, bt, tsb, 1);
  // prep for MFMA logits (aliases: Wp_g over eatt/htat after k_rs; hsT_g over rs after k_head)
  k_prep_w<<<dim3(2688), 256, 0, stream>>>(Wb, Wp_g);
  k_pack_hs<<<dim3(DDD/64, 4096/64), 256, 0, stream>>>(hsb, hsT_g);
  k_zero<<<dim3(405504/1024), 256, 0, stream>>>(out);
  k_logits_mfma<<<dim3(24, 32), 128, 0, stream>>>(hsT_g, tsb, Wp_g, out);
}

// Round 5
// 273.826 us; speedup vs baseline: 6.7352x; 2.2215x over previous
//
#include <hip/hip_runtime.h>
#include <hip/hip_bf16.h>
#include <math.h>

#define NDOC 4
#define CCC  1024
#define DDD  768
#define HHH  12
#define EEE  42
#define MMM  8
#define PPP  1024
#define NBQ  12
#define NK   99
#define NPAD 112

typedef __attribute__((ext_vector_type(8))) short short8v;
typedef __attribute__((ext_vector_type(4))) float floatx4;

__device__ __forceinline__ float bf16_to_f32(unsigned short u) {
  return __builtin_bit_cast(float, ((unsigned int)u) << 16);
}
__device__ __forceinline__ short f32_to_bf16s(float f) {
  return __builtin_bit_cast(short, __float2bfloat16(f));
}
__device__ __forceinline__ unsigned short f32_to_bf16u(float f) {
  return __builtin_bit_cast(unsigned short, __float2bfloat16(f));
}

// ---------------- K1: e_emb = logsumexp over valid mentions (bf16 out) -----
__global__ __launch_bounds__(256) void k_eemb(const float* __restrict__ seq,
    const int* __restrict__ pos, const int* __restrict__ mask,
    unsigned short* __restrict__ eembB) {
  int e = blockIdx.x, doc = blockIdx.y;
  int base = (doc*EEE + e)*MMM;
  int p[MMM], mk[MMM];
#pragma unroll
  for (int m = 0; m < MMM; ++m) { p[m] = pos[base+m] + 1; mk[m] = mask[base+m]; }
  for (int d0 = threadIdx.x; d0 < DDD; d0 += 256) {
    float v[MMM]; float mx = -INFINITY;
#pragma unroll
    for (int m = 0; m < MMM; ++m) {
      v[m] = seq[(doc*CCC + p[m])*DDD + d0];
      if (mk[m]) mx = fmaxf(mx, v[m]);
    }
    float s = 0.f;
#pragma unroll
    for (int m = 0; m < MMM; ++m) if (mk[m]) s += expf(v[m]-mx);
    eembB[(doc*EEE + e)*DDD + d0] = f32_to_bf16u(logf(s) + mx);
  }
}

// ---------------- K2: e_att (fp32) ----------------------------------------
__global__ __launch_bounds__(256) void k_eatt(const float* __restrict__ att,
    const int* __restrict__ pos, const int* __restrict__ mask,
    float* __restrict__ eatt) {
  int head = blockIdx.x, e = blockIdx.y, doc = blockIdx.z;
  int base = (doc*EEE + e)*MMM;
  int j = threadIdx.x * 4;
  float ax=0.f, ay=0.f, az=0.f, aw=0.f; float cnt = 0.f;
#pragma unroll
  for (int m = 0; m < MMM; ++m) {
    int mk = mask[base+m];
    cnt += (float)mk;
    if (mk) {
      int pp = pos[base+m] + 1;
      const float4 a = *(const float4*)&att[((size_t)(doc*HHH + head)*CCC + pp)*CCC + j];
      ax += a.x; ay += a.y; az += a.z; aw += a.w;
    }
  }
  float inv = 1.f / cnt;
  float4 o; o.x = ax*inv; o.y = ay*inv; o.z = az*inv; o.w = aw*inv;
  *(float4*)&eatt[((size_t)((doc*EEE + e)*HHH + head))*CCC + j] = o;
}

// ---------------- K3: ht_att -> bf16 out ----------------------------------
__global__ __launch_bounds__(256) void k_htatt(const float* __restrict__ eatt,
    const int* __restrict__ hts, unsigned short* __restrict__ htB) {
  int b = blockIdx.x; int doc = b >> 10; int r = b & 1023;
  int h0 = hts[(doc*PPP + r)*2 + 0];
  int t0 = hts[(doc*PPP + r)*2 + 1];
  const float* ea0 = &eatt[(size_t)((doc*EEE + h0)*HHH)*CCC];
  const float* ea1 = &eatt[(size_t)((doc*EEE + t0)*HHH)*CCC];
  int j = threadIdx.x * 4;
  float vx=0.f, vy=0.f, vz=0.f, vw=0.f;
#pragma unroll
  for (int hh = 0; hh < HHH; ++hh) {
    const float4 a  = *(const float4*)&ea0[hh*CCC + j];
    const float4 bq = *(const float4*)&ea1[hh*CCC + j];
    vx += a.x*bq.x; vy += a.y*bq.y; vz += a.z*bq.z; vw += a.w*bq.w;
  }
  const float inv12 = 1.f/12.f;
  vx *= inv12; vy *= inv12; vz *= inv12; vw *= inv12;
  float part = vx + vy + vz + vw;
  __shared__ float red[4];
  for (int off = 32; off > 0; off >>= 1) part += __shfl_down(part, off, 64);
  int lane = threadIdx.x & 63, wv = threadIdx.x >> 6;
  if (lane == 0) red[wv] = part;
  __syncthreads();
  if (threadIdx.x == 0) red[0] = red[0]+red[1]+red[2]+red[3];
  __syncthreads();
  float sc = 1.f / (red[0] + 1e-5f);
  unsigned short o[4];
  o[0] = f32_to_bf16u(vx*sc); o[1] = f32_to_bf16u(vy*sc);
  o[2] = f32_to_bf16u(vz*sc); o[3] = f32_to_bf16u(vw*sc);
  *(uint2*)&htB[((size_t)(doc*PPP + r))*CCC + j] = *(const uint2*)o;
}

// ---------------- K3b: pack Wh|Wt -> bf16 [2][768][1536] -------------------
__global__ __launch_bounds__(256) void k_packW(const float* __restrict__ Wh,
    const float* __restrict__ Wt, unsigned short* __restrict__ WB) {
  int gid = blockIdx.x*256 + threadIdx.x;
  int half = gid >= 147456;
  int loc = half ? gid - 147456 : gid;
  const float* src = (half ? Wt : Wh) + (size_t)loc*8;
  float4 v0 = *(const float4*)src;
  float4 v1 = *(const float4*)(src+4);
  unsigned short o[8];
  o[0]=f32_to_bf16u(v0.x); o[1]=f32_to_bf16u(v0.y); o[2]=f32_to_bf16u(v0.z); o[3]=f32_to_bf16u(v0.w);
  o[4]=f32_to_bf16u(v1.x); o[5]=f32_to_bf16u(v1.y); o[6]=f32_to_bf16u(v1.z); o[7]=f32_to_bf16u(v1.w);
  *(uint4*)&WB[(size_t)half*1179648 + (size_t)loc*8] = *(const uint4*)o;
}

// ---------------- K3c: seqT bf16 [doc][768][1024] (transpose) --------------
__global__ __launch_bounds__(256) void k_seqT(const float* __restrict__ seq,
    unsigned short* __restrict__ seqTB) {
  __shared__ float tl[64][65];
  int d0 = blockIdx.x * 64, c0 = blockIdx.y * 64, doc = blockIdx.z;
  int t = threadIdx.x;
#pragma unroll
  for (int rep = 0; rep < 4; ++rep) {
    int cr = rep*16 + (t >> 4);
    int d4 = (t & 15) * 4;
    float4 v = *(const float4*)&seq[((size_t)doc*CCC + c0 + cr)*DDD + d0 + d4];
    tl[cr][d4+0]=v.x; tl[cr][d4+1]=v.y; tl[cr][d4+2]=v.z; tl[cr][d4+3]=v.w;
  }
  __syncthreads();
#pragma unroll
  for (int rep = 0; rep < 4; ++rep) {
    int dr = rep*16 + (t >> 4);
    int c4 = (t & 15) * 4;
    unsigned short o[4];
#pragma unroll
    for (int kq = 0; kq < 4; ++kq)
      o[kq] = f32_to_bf16u(tl[c4+kq][dr]);
    *(uint2*)&seqTB[((size_t)doc*DDD + d0 + dr)*CCC + c0 + c4] = *(const uint2*)o;
  }
}

// ---------------- K4: rs = htatt @ seq  (bf16 MFMA, reg-staged LDS) --------
// grid (6, 32): n0 = bx*128, m0 = by*128. LDS tile layout [row128][q4][8].
__global__ __launch_bounds__(256) void k_rs_mfma(
    const unsigned short* __restrict__ htB,    // [doc][1024][1024]
    const unsigned short* __restrict__ seqTB,  // [doc][768][1024]
    unsigned short* __restrict__ rsB) {        // [4096][768]
  __shared__ unsigned short A_l[4096];
  __shared__ unsigned short B_l[4096];
  const int n0 = blockIdx.x * 128;
  const int m0 = blockIdx.y * 128;
  const int doc = m0 >> 10;
  const int mloc = m0 & 1023;          // doc-local row base (the round-4 bug)
  const int t = threadIdx.x;
  const int lane = t & 63;
  const int ln = lane & 15, q4 = lane >> 4;
  const int w = t >> 6;
  const int wr = w >> 1, wc = w & 1;

  // staging: thread t owns LDS 16B-chunks t and t+256 of each buffer.
  // chunk c -> row c>>2 (0..127), k-offset (c&3)*8.
  const int r0 = t >> 2;              // 0..63 (chunk t); chunk t+256 -> r0+64
  const int koff = (t & 3) * 8;
  const unsigned short* srcA0 = htB + ((size_t)doc*CCC + mloc + r0)*CCC + koff;
  const unsigned short* srcA1 = htB + ((size_t)doc*CCC + mloc + r0 + 64)*CCC + koff;
  const unsigned short* srcB0 = seqTB + ((size_t)doc*DDD + n0 + r0)*CCC + koff;
  const unsigned short* srcB1 = seqTB + ((size_t)doc*DDD + n0 + r0 + 64)*CCC + koff;

  floatx4 acc[4][4];
#pragma unroll
  for (int i = 0; i < 4; ++i)
#pragma unroll
    for (int j = 0; j < 4; ++j) acc[i][j] = (floatx4){0.f,0.f,0.f,0.f};

  for (int k0 = 0; k0 < CCC; k0 += 32) {
    uint4 va0 = *(const uint4*)(srcA0 + k0);
    uint4 va1 = *(const uint4*)(srcA1 + k0);
    uint4 vb0 = *(const uint4*)(srcB0 + k0);
    uint4 vb1 = *(const uint4*)(srcB1 + k0);
    __syncthreads();                 // prior iteration's ds_reads complete
    *(uint4*)&A_l[(size_t)t*8]       = va0;
    *(uint4*)&A_l[(size_t)(t+256)*8] = va1;
    *(uint4*)&B_l[(size_t)t*8]       = vb0;
    *(uint4*)&B_l[(size_t)(t+256)*8] = vb1;
    __syncthreads();                 // staging visible to all waves
    short8v a[4], b[4];
#pragma unroll
    for (int rt = 0; rt < 4; ++rt)
      a[rt] = *(const short8v*)&A_l[((wr*64 + rt*16 + ln)*4 + q4)*8];
#pragma unroll
    for (int nt = 0; nt < 4; ++nt)
      b[nt] = *(const short8v*)&B_l[((wc*64 + nt*16 + ln)*4 + q4)*8];
#pragma unroll
    for (int rt = 0; rt < 4; ++rt)
#pragma unroll
      for (int nt = 0; nt < 4; ++nt)
        acc[rt][nt] = __builtin_amdgcn_mfma_f32_16x16x32_bf16(a[rt], b[nt], acc[rt][nt], 0, 0, 0);
  }
#pragma unroll
  for (int rt = 0; rt < 4; ++rt)
#pragma unroll
    for (int nt = 0; nt < 4; ++nt) {
      int col = n0 + wc*64 + nt*16 + ln;
#pragma unroll
      for (int reg = 0; reg < 4; ++reg) {
        int row = m0 + wr*64 + rt*16 + q4*4 + reg;
        rsB[(size_t)row*DDD + col] = f32_to_bf16u(acc[rt][nt][reg]);
      }
    }
}

// ---------------- K5: heads GEMM (bf16 MFMA, gather-A, tanh epilogue) ------
// grid (6, 32, 2): z=0 -> hs (Wh,bh), z=1 -> ts (Wt,bt). Reg-staged LDS.
__global__ __launch_bounds__(256) void k_heads_mfma(
    const unsigned short* __restrict__ eembB,  // [4*42][768]
    const unsigned short* __restrict__ rsB,    // [4096][768]
    const int* __restrict__ hts,
    const unsigned short* __restrict__ WB,     // [2][768][1536]
    const float* __restrict__ bh, const float* __restrict__ bt,
    float* __restrict__ hsb, float* __restrict__ tsb) {
  __shared__ unsigned short A_l[4096];
  __shared__ unsigned short B_l[4096];
  const int which = blockIdx.z;
  const int n0 = blockIdx.x * 128;
  const int m0 = blockIdx.y * 128;
  const int doc = m0 >> 10;
  const int t = threadIdx.x;
  const int lane = t & 63;
  const int ln = lane & 15, q4 = lane >> 4;
  const int w = t >> 6;
  const int wr = w >> 1, wc = w & 1;

  const int r0 = t >> 2;
  const int koff = (t & 3) * 8;
  const int rgA0 = m0 + r0, rgA1 = m0 + r0 + 64;   // global rows (0..4095)
  const int idx0 = hts[rgA0*2 + which];
  const int idx1 = hts[rgA1*2 + which];
  const unsigned short* srcE0 = eembB + (size_t)(doc*EEE + idx0)*DDD + koff;
  const unsigned short* srcE1 = eembB + (size_t)(doc*EEE + idx1)*DDD + koff;
  const unsigned short* srcR0 = rsB + (size_t)rgA0*DDD + koff;
  const unsigned short* srcR1 = rsB + (size_t)rgA1*DDD + koff;
  const unsigned short* WBz = WB + (size_t)which*1179648;
  const unsigned short* srcW0 = WBz + (size_t)(n0 + r0)*1536 + koff;
  const unsigned short* srcW1 = WBz + (size_t)(n0 + r0 + 64)*1536 + koff;

  floatx4 acc[4][4];
#pragma unroll
  for (int i = 0; i < 4; ++i)
#pragma unroll
    for (int j = 0; j < 4; ++j) acc[i][j] = (floatx4){0.f,0.f,0.f,0.f};

  for (int k0 = 0; k0 < 1536; k0 += 32) {
    uint4 va0 = (k0 < DDD) ? *(const uint4*)(srcE0 + k0) : *(const uint4*)(srcR0 + (k0 - DDD));
    uint4 va1 = (k0 < DDD) ? *(const uint4*)(srcE1 + k0) : *(const uint4*)(srcR1 + (k0 - DDD));
    uint4 vb0 = *(const uint4*)(srcW0 + k0);
    uint4 vb1 = *(const uint4*)(srcW1 + k0);
    __syncthreads();
    *(uint4*)&A_l[(size_t)t*8]       = va0;
    *(uint4*)&A_l[(size_t)(t+256)*8] = va1;
    *(uint4*)&B_l[(size_t)t*8]       = vb0;
    *(uint4*)&B_l[(size_t)(t+256)*8] = vb1;
    __syncthreads();
    short8v a[4], b[4];
#pragma unroll
    for (int rt = 0; rt < 4; ++rt)
      a[rt] = *(const short8v*)&A_l[((wr*64 + rt*16 + ln)*4 + q4)*8];
#pragma unroll
    for (int nt = 0; nt < 4; ++nt)
      b[nt] = *(const short8v*)&B_l[((wc*64 + nt*16 + ln)*4 + q4)*8];
#pragma unroll
    for (int rt = 0; rt < 4; ++rt)
#pragma unroll
      for (int nt = 0; nt < 4; ++nt)
        acc[rt][nt] = __builtin_amdgcn_mfma_f32_16x16x32_bf16(a[rt], b[nt], acc[rt][nt], 0, 0, 0);
  }
  const float* bias = which ? bt : bh;
  float* outp = which ? tsb : hsb;
#pragma unroll
  for (int rt = 0; rt < 4; ++rt)
#pragma unroll
    for (int nt = 0; nt < 4; ++nt) {
      int col = n0 + wc*64 + nt*16 + ln;
      float bsv = bias[col];
#pragma unroll
      for (int reg = 0; reg < 4; ++reg) {
        int row = m0 + wr*64 + rt*16 + q4*4 + reg;
        outp[(size_t)row*DDD + col] = tanhf(acc[rt][nt][reg] + bsv);
      }
    }
}

// ------- K6a: pack Wb fp32 [99][49152] -> bf16 tiles Wp[ki][n(112)][j(64)] --
__global__ __launch_bounds__(256) void k_prep_w(const float* __restrict__ Wb,
    unsigned short* __restrict__ Wp) {
  int t = blockIdx.x*256 + threadIdx.x;
  int j = (t & 7) * 8;
  int n = (t >> 3) % NPAD;
  int ki = t / 896;
  unsigned short o[8];
  if (n < NK) {
    const float* src = &Wb[(size_t)n*49152 + ki*64 + j];
    float4 v0 = *(const float4*)src;
    float4 v1 = *(const float4*)(src+4);
    o[0]=f32_to_bf16u(v0.x); o[1]=f32_to_bf16u(v0.y); o[2]=f32_to_bf16u(v0.z); o[3]=f32_to_bf16u(v0.w);
    o[4]=f32_to_bf16u(v1.x); o[5]=f32_to_bf16u(v1.y); o[6]=f32_to_bf16u(v1.z); o[7]=f32_to_bf16u(v1.w);
  } else {
#pragma unroll
    for (int e=0;e<8;++e) o[e]=0;
  }
  *(uint4*)&Wp[(size_t)ki*7168 + n*64 + j] = *(const uint4*)o;
}

// ------- K6b: hsT_g[i][r] = bf16(hs[r][i]) ---------------------------------
__global__ __launch_bounds__(256) void k_pack_hs(const float* __restrict__ hs,
    unsigned short* __restrict__ hsT) {
  __shared__ float tl[64][65];
  int i0 = blockIdx.x * 64, r0 = blockIdx.y * 64;
  int t = threadIdx.x;
#pragma unroll
  for (int rep = 0; rep < 4; ++rep) {
    int r = rep*16 + (t >> 4);
    int c4 = (t & 15) * 4;
    float4 v = *(const float4*)&hs[(size_t)(r0 + r)*DDD + i0 + c4];
    tl[r][c4+0]=v.x; tl[r][c4+1]=v.y; tl[r][c4+2]=v.z; tl[r][c4+3]=v.w;
  }
  __syncthreads();
#pragma unroll
  for (int rep = 0; rep < 4; ++rep) {
    int i = rep*16 + (t >> 4);
    int r4 = (t & 15) * 4;
    unsigned short o[4];
#pragma unroll
    for (int kq = 0; kq < 4; ++kq)
      o[kq] = f32_to_bf16u(tl[r4+kq][i]);
    *(uint2*)&hsT[(size_t)(i0 + i)*4096 + r0 + r4] = *(const uint2*)o;
  }
}

// ------- K6c: zero logits --------------------------------------------------
__global__ __launch_bounds__(256) void k_zero(float* __restrict__ p) {
  int t = blockIdx.x*256 + threadIdx.x;
  float4 z; z.x=z.y=z.z=z.w=0.f;
  *(float4*)&p[(size_t)t*4] = z;
}

// ------- K6: logits via bf16 MFMA, A = outer(hs,ts) generated on the fly ---
__global__ __launch_bounds__(128, 2) void k_logits_mfma(
    const unsigned short* __restrict__ hsT,   // [768][4096] bf16
    const float* __restrict__ tsb,            // [4096][768] fp32
    const unsigned short* __restrict__ Wp,    // [768 ki][112 n][64 j] bf16
    float* __restrict__ logits) {
  __shared__ unsigned short hsT_l[32*128];
  __shared__ unsigned short Bt_l[NPAD*72];
  const int nb = blockIdx.x >> 1;
  const int ih = (blockIdx.x & 1) * 32;
  const int mtile = blockIdx.y;
  const int t = threadIdx.x;
  const int w = t >> 6;
  const int lane = t & 63;
  const int ln = lane & 15;
  const int q = lane >> 4;
  const int m0w = mtile*128 + w*64;

#pragma unroll
  for (int rep = 0; rep < 4; ++rep) {
    int c16 = t + rep*128;
    int ii = c16 >> 4;
    int c8 = (c16 & 15) * 8;
    uint4 v = *(const uint4*)&hsT[(size_t)(nb*64 + ih + ii)*4096 + mtile*128 + c8];
    *(uint4*)&hsT_l[ii*128 + c8] = v;
  }

  float tsr[4][2][8];
#pragma unroll
  for (int rt = 0; rt < 4; ++rt) {
    int row = m0w + rt*16 + ln;
#pragma unroll
    for (int js = 0; js < 2; ++js) {
      const float* p = &tsb[(size_t)row*DDD + nb*64 + js*32 + q*8];
      float4 v0 = *(const float4*)p;
      float4 v1 = *(const float4*)(p+4);
      tsr[rt][js][0]=v0.x; tsr[rt][js][1]=v0.y; tsr[rt][js][2]=v0.z; tsr[rt][js][3]=v0.w;
      tsr[rt][js][4]=v1.x; tsr[rt][js][5]=v1.y; tsr[rt][js][6]=v1.z; tsr[rt][js][7]=v1.w;
    }
  }

  floatx4 acc[4][7];
#pragma unroll
  for (int rt = 0; rt < 4; ++rt)
#pragma unroll
    for (int nt = 0; nt < 7; ++nt)
      acc[rt][nt] = (floatx4){0.f,0.f,0.f,0.f};

  for (int ii = 0; ii < 32; ++ii) {
    const int ki = nb*64 + ih + ii;
    uint4 wreg[7];
#pragma unroll
    for (int r = 0; r < 7; ++r) {
      int chunk = t + r*128;
      wreg[r] = *(const uint4*)&Wp[(size_t)ki*7168 + chunk*8];
    }
    __syncthreads();
#pragma unroll
    for (int r = 0; r < 7; ++r) {
      int chunk = t + r*128;
      int n = chunk >> 3, j8 = (chunk & 7)*8;
      *(uint4*)&Bt_l[n*72 + j8] = wreg[r];
    }
    __syncthreads();

    float h[4];
#pragma unroll
    for (int rt = 0; rt < 4; ++rt)
      h[rt] = bf16_to_f32(hsT_l[ii*128 + w*64 + rt*16 + ln]);

#pragma unroll
    for (int js = 0; js < 2; ++js) {
      short8v a[4];
#pragma unroll
      for (int rt = 0; rt < 4; ++rt) {
#pragma unroll
        for (int e = 0; e < 8; ++e)
          a[rt][e] = f32_to_bf16s(h[rt] * tsr[rt][js][e]);
      }
      short8v b[7];
#pragma unroll
      for (int nt = 0; nt < 7; ++nt)
        b[nt] = *(const short8v*)&Bt_l[(nt*16 + ln)*72 + js*32 + q*8];
#pragma unroll
      for (int rt = 0; rt < 4; ++rt)
#pragma unroll
        for (int nt = 0; nt < 7; ++nt)
          acc[rt][nt] = __builtin_amdgcn_mfma_f32_16x16x32_bf16(a[rt], b[nt], acc[rt][nt], 0, 0, 0);
    }
  }

#pragma unroll
  for (int nt = 0; nt < 7; ++nt) {
    int col = nt*16 + ln;
    if (col < NK) {
#pragma unroll
      for (int rt = 0; rt < 4; ++rt) {
#pragma unroll
        for (int reg = 0; reg < 4; ++reg) {
          int row = m0w + rt*16 + q*4 + reg;
          atomicAdd(&logits[(size_t)row*NK + col], acc[rt][nt][reg]);
        }
      }
    }
  }
}

extern "C" void kernel_launch(void* const* d_in, const int* in_sizes, int n_in,
                              void* d_out, int out_size, void* d_ws, size_t ws_size,
                              hipStream_t stream) {
  const float* seq  = (const float*)d_in[0];
  const float* att  = (const float*)d_in[1];
  const float* Wh   = (const float*)d_in[2];
  const float* bh   = (const float*)d_in[3];
  const float* Wt   = (const float*)d_in[4];
  const float* bt   = (const float*)d_in[5];
  const float* Wb   = (const float*)d_in[6];
  const int* pos    = (const int*)d_in[7];
  const int* mask   = (const int*)d_in[8];
  const int* hts    = (const int*)d_in[9];
  float* out = (float*)d_out;

  float* ws = (float*)d_ws;
  // layout (float slots), total 14,842,880 f = 59.4 MB
  float*          eatt  = ws;                                   // 2,064,384 f
  unsigned short* htB   = (unsigned short*)(ws + 2064384);      // 4,194,304 us
  unsigned short* eembB = (unsigned short*)(ws + 4161536);      //   129,024 us
  unsigned short* seqTB = (unsigned short*)(ws + 4226048);      // 3,145,728 us
  unsigned short* WhtB  = (unsigned short*)(ws + 5798912);      // 2,359,296 us
  unsigned short* rsB   = (unsigned short*)(ws + 6978560);      // 3,145,728 us
  float*          hsb   = ws + 8551424;                         // 3,145,728 f
  float*          tsb   = ws + 11697152;                        // 3,145,728 f
  // aliases (valid by launch order):
  unsigned short* WpB   = (unsigned short*)eatt;   // 5,505,024 us <= eatt+htB span; written after k_rs_mfma
  unsigned short* hsTB  = (unsigned short*)seqTB;  // 3,145,728 us = seqTB span; written after k_rs_mfma

  k_eemb<<<dim3(EEE, NDOC), 256, 0, stream>>>(seq, pos, mask, eembB);
  k_eatt<<<dim3(HHH, EEE, NDOC), 256, 0, stream>>>(att, pos, mask, eatt);
  k_htatt<<<dim3(NDOC*PPP), 256, 0, stream>>>(eatt, hts, htB);
  k_packW<<<dim3(1152), 256, 0, stream>>>(Wh, Wt, WhtB);
  k_seqT<<<dim3(DDD/64, CCC/64, NDOC), 256, 0, stream>>>(seq, seqTB);
  k_rs_mfma<<<dim3(6, 32), 256, 0, stream>>>(htB, seqTB, rsB);
  k_prep_w<<<dim3(2688), 256, 0, stream>>>(Wb, WpB);
  k_heads_mfma<<<dim3(6, 32, 2), 256, 0, stream>>>(eembB, rsB, hts, WhtB, bh, bt, hsb, tsb);
  k_pack_hs<<<dim3(DDD/64, 4096/64), 256, 0, stream>>>(hsb, hsTB);
  k_zero<<<dim3(396), 256, 0, stream>>>(out);
  k_logits_mfma<<<dim3(24, 32), 128, 0, stream>>>(hsTB, tsb, WpB, out);
}

// Round 6
// 273.737 us; speedup vs baseline: 6.7374x; 1.0003x over previous
//
#include <hip/hip_runtime.h>
#include <hip/hip_bf16.h>
#include <math.h>

#define NDOC 4
#define CCC  1024
#define DDD  768
#define HHH  12
#define EEE  42
#define MMM  8
#define PPP  1024
#define NBQ  12
#define NK   99
#define NPAD 112

typedef __attribute__((ext_vector_type(8))) short short8v;
typedef __attribute__((ext_vector_type(4))) float floatx4;

__device__ __forceinline__ float bf16_to_f32(unsigned short u) {
  return __builtin_bit_cast(float, ((unsigned int)u) << 16);
}
__device__ __forceinline__ short f32_to_bf16s(float f) {
  return __builtin_bit_cast(short, __float2bfloat16(f));
}
__device__ __forceinline__ unsigned short f32_to_bf16u(float f) {
  return __builtin_bit_cast(unsigned short, __float2bfloat16(f));
}

// ---------------- K1: e_emb = logsumexp over valid mentions (bf16 out) -----
__global__ __launch_bounds__(256) void k_eemb(const float* __restrict__ seq,
    const int* __restrict__ pos, const int* __restrict__ mask,
    unsigned short* __restrict__ eembB) {
  int e = blockIdx.x, doc = blockIdx.y;
  int base = (doc*EEE + e)*MMM;
  int p[MMM], mk[MMM];
#pragma unroll
  for (int m = 0; m < MMM; ++m) { p[m] = pos[base+m] + 1; mk[m] = mask[base+m]; }
  for (int d0 = threadIdx.x; d0 < DDD; d0 += 256) {
    float v[MMM]; float mx = -INFINITY;
#pragma unroll
    for (int m = 0; m < MMM; ++m) {
      v[m] = seq[(doc*CCC + p[m])*DDD + d0];
      if (mk[m]) mx = fmaxf(mx, v[m]);
    }
    float s = 0.f;
#pragma unroll
    for (int m = 0; m < MMM; ++m) if (mk[m]) s += expf(v[m]-mx);
    eembB[(doc*EEE + e)*DDD + d0] = f32_to_bf16u(logf(s) + mx);
  }
}

// ---------------- K2: e_att (fp32) ----------------------------------------
__global__ __launch_bounds__(256) void k_eatt(const float* __restrict__ att,
    const int* __restrict__ pos, const int* __restrict__ mask,
    float* __restrict__ eatt) {
  int head = blockIdx.x, e = blockIdx.y, doc = blockIdx.z;
  int base = (doc*EEE + e)*MMM;
  int j = threadIdx.x * 4;
  float ax=0.f, ay=0.f, az=0.f, aw=0.f; float cnt = 0.f;
#pragma unroll
  for (int m = 0; m < MMM; ++m) {
    int mk = mask[base+m];
    cnt += (float)mk;
    if (mk) {
      int pp = pos[base+m] + 1;
      const float4 a = *(const float4*)&att[((size_t)(doc*HHH + head)*CCC + pp)*CCC + j];
      ax += a.x; ay += a.y; az += a.z; aw += a.w;
    }
  }
  float inv = 1.f / cnt;
  float4 o; o.x = ax*inv; o.y = ay*inv; o.z = az*inv; o.w = aw*inv;
  *(float4*)&eatt[((size_t)((doc*EEE + e)*HHH + head))*CCC + j] = o;
}

// ---------------- K3: ht_att -> bf16 out ----------------------------------
__global__ __launch_bounds__(256) void k_htatt(const float* __restrict__ eatt,
    const int* __restrict__ hts, unsigned short* __restrict__ htB) {
  int b = blockIdx.x; int doc = b >> 10; int r = b & 1023;
  int h0 = hts[(doc*PPP + r)*2 + 0];
  int t0 = hts[(doc*PPP + r)*2 + 1];
  const float* ea0 = &eatt[(size_t)((doc*EEE + h0)*HHH)*CCC];
  const float* ea1 = &eatt[(size_t)((doc*EEE + t0)*HHH)*CCC];
  int j = threadIdx.x * 4;
  float vx=0.f, vy=0.f, vz=0.f, vw=0.f;
#pragma unroll
  for (int hh = 0; hh < HHH; ++hh) {
    const float4 a  = *(const float4*)&ea0[hh*CCC + j];
    const float4 bq = *(const float4*)&ea1[hh*CCC + j];
    vx += a.x*bq.x; vy += a.y*bq.y; vz += a.z*bq.z; vw += a.w*bq.w;
  }
  const float inv12 = 1.f/12.f;
  vx *= inv12; vy *= inv12; vz *= inv12; vw *= inv12;
  float part = vx + vy + vz + vw;
  __shared__ float red[4];
  for (int off = 32; off > 0; off >>= 1) part += __shfl_down(part, off, 64);
  int lane = threadIdx.x & 63, wv = threadIdx.x >> 6;
  if (lane == 0) red[wv] = part;
  __syncthreads();
  if (threadIdx.x == 0) red[0] = red[0]+red[1]+red[2]+red[3];
  __syncthreads();
  float sc = 1.f / (red[0] + 1e-5f);
  unsigned short o[4];
  o[0] = f32_to_bf16u(vx*sc); o[1] = f32_to_bf16u(vy*sc);
  o[2] = f32_to_bf16u(vz*sc); o[3] = f32_to_bf16u(vw*sc);
  *(uint2*)&htB[((size_t)(doc*PPP + r))*CCC + j] = *(const uint2*)o;
}

// ---------------- K3b: pack Wh|Wt -> bf16 [2][768][1536] -------------------
__global__ __launch_bounds__(256) void k_packW(const float* __restrict__ Wh,
    const float* __restrict__ Wt, unsigned short* __restrict__ WB) {
  int gid = blockIdx.x*256 + threadIdx.x;
  int half = gid >= 147456;
  int loc = half ? gid - 147456 : gid;
  const float* src = (half ? Wt : Wh) + (size_t)loc*8;
  float4 v0 = *(const float4*)src;
  float4 v1 = *(const float4*)(src+4);
  unsigned short o[8];
  o[0]=f32_to_bf16u(v0.x); o[1]=f32_to_bf16u(v0.y); o[2]=f32_to_bf16u(v0.z); o[3]=f32_to_bf16u(v0.w);
  o[4]=f32_to_bf16u(v1.x); o[5]=f32_to_bf16u(v1.y); o[6]=f32_to_bf16u(v1.z); o[7]=f32_to_bf16u(v1.w);
  *(uint4*)&WB[(size_t)half*1179648 + (size_t)loc*8] = *(const uint4*)o;
}

// ---------------- K3c: seqT bf16 [doc][768][1024] (transpose) --------------
__global__ __launch_bounds__(256) void k_seqT(const float* __restrict__ seq,
    unsigned short* __restrict__ seqTB) {
  __shared__ float tl[64][65];
  int d0 = blockIdx.x * 64, c0 = blockIdx.y * 64, doc = blockIdx.z;
  int t = threadIdx.x;
#pragma unroll
  for (int rep = 0; rep < 4; ++rep) {
    int cr = rep*16 + (t >> 4);
    int d4 = (t & 15) * 4;
    float4 v = *(const float4*)&seq[((size_t)doc*CCC + c0 + cr)*DDD + d0 + d4];
    tl[cr][d4+0]=v.x; tl[cr][d4+1]=v.y; tl[cr][d4+2]=v.z; tl[cr][d4+3]=v.w;
  }
  __syncthreads();
#pragma unroll
  for (int rep = 0; rep < 4; ++rep) {
    int dr = rep*16 + (t >> 4);
    int c4 = (t & 15) * 4;
    unsigned short o[4];
#pragma unroll
    for (int kq = 0; kq < 4; ++kq)
      o[kq] = f32_to_bf16u(tl[c4+kq][dr]);
    *(uint2*)&seqTB[((size_t)doc*DDD + d0 + dr)*CCC + c0 + c4] = *(const uint2*)o;
  }
}

// ---------------- K4: rs = htatt @ seq  (bf16 MFMA, reg-staged LDS) --------
// grid (6, 32): n0 = bx*128, m0 = by*128. LDS tile layout [row128][q4][8].
__global__ __launch_bounds__(256) void k_rs_mfma(
    const unsigned short* __restrict__ htB,    // [doc][1024][1024]
    const unsigned short* __restrict__ seqTB,  // [doc][768][1024]
    unsigned short* __restrict__ rsB) {        // [4096][768]
  __shared__ unsigned short A_l[4096];
  __shared__ unsigned short B_l[4096];
  const int n0 = blockIdx.x * 128;
  const int m0 = blockIdx.y * 128;
  const int doc = m0 >> 10;
  const int mloc = m0 & 1023;          // doc-local row base (the round-4 bug)
  const int t = threadIdx.x;
  const int lane = t & 63;
  const int ln = lane & 15, q4 = lane >> 4;
  const int w = t >> 6;
  const int wr = w >> 1, wc = w & 1;

  // staging: thread t owns LDS 16B-chunks t and t+256 of each buffer.
  // chunk c -> row c>>2 (0..127), k-offset (c&3)*8.
  const int r0 = t >> 2;              // 0..63 (chunk t); chunk t+256 -> r0+64
  const int koff = (t & 3) * 8;
  const unsigned short* srcA0 = htB + ((size_t)doc*CCC + mloc + r0)*CCC + koff;
  const unsigned short* srcA1 = htB + ((size_t)doc*CCC + mloc + r0 + 64)*CCC + koff;
  const unsigned short* srcB0 = seqTB + ((size_t)doc*DDD + n0 + r0)*CCC + koff;
  const unsigned short* srcB1 = seqTB + ((size_t)doc*DDD + n0 + r0 + 64)*CCC + koff;

  floatx4 acc[4][4];
#pragma unroll
  for (int i = 0; i < 4; ++i)
#pragma unroll
    for (int j = 0; j < 4; ++j) acc[i][j] = (floatx4){0.f,0.f,0.f,0.f};

  for (int k0 = 0; k0 < CCC; k0 += 32) {
    uint4 va0 = *(const uint4*)(srcA0 + k0);
    uint4 va1 = *(const uint4*)(srcA1 + k0);
    uint4 vb0 = *(const uint4*)(srcB0 + k0);
    uint4 vb1 = *(const uint4*)(srcB1 + k0);
    __syncthreads();                 // prior iteration's ds_reads complete
    *(uint4*)&A_l[(size_t)t*8]       = va0;
    *(uint4*)&A_l[(size_t)(t+256)*8] = va1;
    *(uint4*)&B_l[(size_t)t*8]       = vb0;
    *(uint4*)&B_l[(size_t)(t+256)*8] = vb1;
    __syncthreads();                 // staging visible to all waves
    short8v a[4], b[4];
#pragma unroll
    for (int rt = 0; rt < 4; ++rt)
      a[rt] = *(const short8v*)&A_l[((wr*64 + rt*16 + ln)*4 + q4)*8];
#pragma unroll
    for (int nt = 0; nt < 4; ++nt)
      b[nt] = *(const short8v*)&B_l[((wc*64 + nt*16 + ln)*4 + q4)*8];
#pragma unroll
    for (int rt = 0; rt < 4; ++rt)
#pragma unroll
      for (int nt = 0; nt < 4; ++nt)
        acc[rt][nt] = __builtin_amdgcn_mfma_f32_16x16x32_bf16(a[rt], b[nt], acc[rt][nt], 0, 0, 0);
  }
#pragma unroll
  for (int rt = 0; rt < 4; ++rt)
#pragma unroll
    for (int nt = 0; nt < 4; ++nt) {
      int col = n0 + wc*64 + nt*16 + ln;
#pragma unroll
      for (int reg = 0; reg < 4; ++reg) {
        int row = m0 + wr*64 + rt*16 + q4*4 + reg;
        rsB[(size_t)row*DDD + col] = f32_to_bf16u(acc[rt][nt][reg]);
      }
    }
}

// ---------------- K5: heads GEMM (bf16 MFMA, gather-A, tanh epilogue) ------
// grid (6, 32, 2): z=0 -> hs (Wh,bh), z=1 -> ts (Wt,bt). Reg-staged LDS.
__global__ __launch_bounds__(256) void k_heads_mfma(
    const unsigned short* __restrict__ eembB,  // [4*42][768]
    const unsigned short* __restrict__ rsB,    // [4096][768]
    const int* __restrict__ hts,
    const unsigned short* __restrict__ WB,     // [2][768][1536]
    const float* __restrict__ bh, const float* __restrict__ bt,
    float* __restrict__ hsb, float* __restrict__ tsb) {
  __shared__ unsigned short A_l[4096];
  __shared__ unsigned short B_l[4096];
  const int which = blockIdx.z;
  const int n0 = blockIdx.x * 128;
  const int m0 = blockIdx.y * 128;
  const int doc = m0 >> 10;
  const int t = threadIdx.x;
  const int lane = t & 63;
  const int ln = lane & 15, q4 = lane >> 4;
  const int w = t >> 6;
  const int wr = w >> 1, wc = w & 1;

  const int r0 = t >> 2;
  const int koff = (t & 3) * 8;
  const int rgA0 = m0 + r0, rgA1 = m0 + r0 + 64;   // global rows (0..4095)
  const int idx0 = hts[rgA0*2 + which];
  const int idx1 = hts[rgA1*2 + which];
  const unsigned short* srcE0 = eembB + (size_t)(doc*EEE + idx0)*DDD + koff;
  const unsigned short* srcE1 = eembB + (size_t)(doc*EEE + idx1)*DDD + koff;
  const unsigned short* srcR0 = rsB + (size_t)rgA0*DDD + koff;
  const unsigned short* srcR1 = rsB + (size_t)rgA1*DDD + koff;
  const unsigned short* WBz = WB + (size_t)which*1179648;
  const unsigned short* srcW0 = WBz + (size_t)(n0 + r0)*1536 + koff;
  const unsigned short* srcW1 = WBz + (size_t)(n0 + r0 + 64)*1536 + koff;

  floatx4 acc[4][4];
#pragma unroll
  for (int i = 0; i < 4; ++i)
#pragma unroll
    for (int j = 0; j < 4; ++j) acc[i][j] = (floatx4){0.f,0.f,0.f,0.f};

  for (int k0 = 0; k0 < 1536; k0 += 32) {
    uint4 va0 = (k0 < DDD) ? *(const uint4*)(srcE0 + k0) : *(const uint4*)(srcR0 + (k0 - DDD));
    uint4 va1 = (k0 < DDD) ? *(const uint4*)(srcE1 + k0) : *(const uint4*)(srcR1 + (k0 - DDD));
    uint4 vb0 = *(const uint4*)(srcW0 + k0);
    uint4 vb1 = *(const uint4*)(srcW1 + k0);
    __syncthreads();
    *(uint4*)&A_l[(size_t)t*8]       = va0;
    *(uint4*)&A_l[(size_t)(t+256)*8] = va1;
    *(uint4*)&B_l[(size_t)t*8]       = vb0;
    *(uint4*)&B_l[(size_t)(t+256)*8] = vb1;
    __syncthreads();
    short8v a[4], b[4];
#pragma unroll
    for (int rt = 0; rt < 4; ++rt)
      a[rt] = *(const short8v*)&A_l[((wr*64 + rt*16 + ln)*4 + q4)*8];
#pragma unroll
    for (int nt = 0; nt < 4; ++nt)
      b[nt] = *(const short8v*)&B_l[((wc*64 + nt*16 + ln)*4 + q4)*8];
#pragma unroll
    for (int rt = 0; rt < 4; ++rt)
#pragma unroll
      for (int nt = 0; nt < 4; ++nt)
        acc[rt][nt] = __builtin_amdgcn_mfma_f32_16x16x32_bf16(a[rt], b[nt], acc[rt][nt], 0, 0, 0);
  }
  const float* bias = which ? bt : bh;
  float* outp = which ? tsb : hsb;
#pragma unroll
  for (int rt = 0; rt < 4; ++rt)
#pragma unroll
    for (int nt = 0; nt < 4; ++nt) {
      int col = n0 + wc*64 + nt*16 + ln;
      float bsv = bias[col];
#pragma unroll
      for (int reg = 0; reg < 4; ++reg) {
        int row = m0 + wr*64 + rt*16 + q4*4 + reg;
        outp[(size_t)row*DDD + col] = tanhf(acc[rt][nt][reg] + bsv);
      }
    }
}

// ------- K6a: pack Wb fp32 [99][49152] -> bf16 tiles Wp[ki][n(112)][j(64)] --
__global__ __launch_bounds__(256) void k_prep_w(const float* __restrict__ Wb,
    unsigned short* __restrict__ Wp) {
  int t = blockIdx.x*256 + threadIdx.x;
  int j = (t & 7) * 8;
  int n = (t >> 3) % NPAD;
  int ki = t / 896;
  unsigned short o[8];
  if (n < NK) {
    const float* src = &Wb[(size_t)n*49152 + ki*64 + j];
    float4 v0 = *(const float4*)src;
    float4 v1 = *(const float4*)(src+4);
    o[0]=f32_to_bf16u(v0.x); o[1]=f32_to_bf16u(v0.y); o[2]=f32_to_bf16u(v0.z); o[3]=f32_to_bf16u(v0.w);
    o[4]=f32_to_bf16u(v1.x); o[5]=f32_to_bf16u(v1.y); o[6]=f32_to_bf16u(v1.z); o[7]=f32_to_bf16u(v1.w);
  } else {
#pragma unroll
    for (int e=0;e<8;++e) o[e]=0;
  }
  *(uint4*)&Wp[(size_t)ki*7168 + n*64 + j] = *(const uint4*)o;
}

// ------- K6b: hsT_g[i][r] = bf16(hs[r][i]) ---------------------------------
__global__ __launch_bounds__(256) void k_pack_hs(const float* __restrict__ hs,
    unsigned short* __restrict__ hsT) {
  __shared__ float tl[64][65];
  int i0 = blockIdx.x * 64, r0 = blockIdx.y * 64;
  int t = threadIdx.x;
#pragma unroll
  for (int rep = 0; rep < 4; ++rep) {
    int r = rep*16 + (t >> 4);
    int c4 = (t & 15) * 4;
    float4 v = *(const float4*)&hs[(size_t)(r0 + r)*DDD + i0 + c4];
    tl[r][c4+0]=v.x; tl[r][c4+1]=v.y; tl[r][c4+2]=v.z; tl[r][c4+3]=v.w;
  }
  __syncthreads();
#pragma unroll
  for (int rep = 0; rep < 4; ++rep) {
    int i = rep*16 + (t >> 4);
    int r4 = (t & 15) * 4;
    unsigned short o[4];
#pragma unroll
    for (int kq = 0; kq < 4; ++kq)
      o[kq] = f32_to_bf16u(tl[r4+kq][i]);
    *(uint2*)&hsT[(size_t)(i0 + i)*4096 + r0 + r4] = *(const uint2*)o;
  }
}

// ------- K6c: zero logits --------------------------------------------------
__global__ __launch_bounds__(256) void k_zero(float* __restrict__ p) {
  int t = blockIdx.x*256 + threadIdx.x;
  float4 z; z.x=z.y=z.z=z.w=0.f;
  *(float4*)&p[(size_t)t*4] = z;
}

// ------- K6: logits via bf16 MFMA, A = outer(hs,ts) generated on the fly ---
__global__ __launch_bounds__(128, 2) void k_logits_mfma(
    const unsigned short* __restrict__ hsT,   // [768][4096] bf16
    const float* __restrict__ tsb,            // [4096][768] fp32
    const unsigned short* __restrict__ Wp,    // [768 ki][112 n][64 j] bf16
    float* __restrict__ logits) {
  __shared__ unsigned short hsT_l[32*128];
  __shared__ unsigned short Bt_l[NPAD*72];
  const int nb = blockIdx.x >> 1;
  const int ih = (blockIdx.x & 1) * 32;
  const int mtile = blockIdx.y;
  const int t = threadIdx.x;
  const int w = t >> 6;
  const int lane = t & 63;
  const int ln = lane & 15;
  const int q = lane >> 4;
  const int m0w = mtile*128 + w*64;

#pragma unroll
  for (int rep = 0; rep < 4; ++rep) {
    int c16 = t + rep*128;
    int ii = c16 >> 4;
    int c8 = (c16 & 15) * 8;
    uint4 v = *(const uint4*)&hsT[(size_t)(nb*64 + ih + ii)*4096 + mtile*128 + c8];
    *(uint4*)&hsT_l[ii*128 + c8] = v;
  }

  float tsr[4][2][8];
#pragma unroll
  for (int rt = 0; rt < 4; ++rt) {
    int row = m0w + rt*16 + ln;
#pragma unroll
    for (int js = 0; js < 2; ++js) {
      const float* p = &tsb[(size_t)row*DDD + nb*64 + js*32 + q*8];
      float4 v0 = *(const float4*)p;
      float4 v1 = *(const float4*)(p+4);
      tsr[rt][js][0]=v0.x; tsr[rt][js][1]=v0.y; tsr[rt][js][2]=v0.z; tsr[rt][js][3]=v0.w;
      tsr[rt][js][4]=v1.x; tsr[rt][js][5]=v1.y; tsr[rt][js][6]=v1.z; tsr[rt][js][7]=v1.w;
    }
  }

  floatx4 acc[4][7];
#pragma unroll
  for (int rt = 0; rt < 4; ++rt)
#pragma unroll
    for (int nt = 0; nt < 7; ++nt)
      acc[rt][nt] = (floatx4){0.f,0.f,0.f,0.f};

  for (int ii = 0; ii < 32; ++ii) {
    const int ki = nb*64 + ih + ii;
    uint4 wreg[7];
#pragma unroll
    for (int r = 0; r < 7; ++r) {
      int chunk = t + r*128;
      wreg[r] = *(const uint4*)&Wp[(size_t)ki*7168 + chunk*8];
    }
    __syncthreads();
#pragma unroll
    for (int r = 0; r < 7; ++r) {
      int chunk = t + r*128;
      int n = chunk >> 3, j8 = (chunk & 7)*8;
      *(uint4*)&Bt_l[n*72 + j8] = wreg[r];
    }
    __syncthreads();

    float h[4];
#pragma unroll
    for (int rt = 0; rt < 4; ++rt)
      h[rt] = bf16_to_f32(hsT_l[ii*128 + w*64 + rt*16 + ln]);

#pragma unroll
    for (int js = 0; js < 2; ++js) {
      short8v a[4];
#pragma unroll
      for (int rt = 0; rt < 4; ++rt) {
#pragma unroll
        for (int e = 0; e < 8; ++e)
          a[rt][e] = f32_to_bf16s(h[rt] * tsr[rt][js][e]);
      }
      short8v b[7];
#pragma unroll
      for (int nt = 0; nt < 7; ++nt)
        b[nt] = *(const short8v*)&Bt_l[(nt*16 + ln)*72 + js*32 + q*8];
#pragma unroll
      for (int rt = 0; rt < 4; ++rt)
#pragma unroll
        for (int nt = 0; nt < 7; ++nt)
          acc[rt][nt] = __builtin_amdgcn_mfma_f32_16x16x32_bf16(a[rt], b[nt], acc[rt][nt], 0, 0, 0);
    }
  }

#pragma unroll
  for (int nt = 0; nt < 7; ++nt) {
    int col = nt*16 + ln;
    if (col < NK) {
#pragma unroll
      for (int rt = 0; rt < 4; ++rt) {
#pragma unroll
        for (int reg = 0; reg < 4; ++reg) {
          int row = m0w + rt*16 + q*4 + reg;
          atomicAdd(&logits[(size_t)row*NK + col], acc[rt][nt][reg]);
        }
      }
    }
  }
}

extern "C" void kernel_launch(void* const* d_in, const int* in_sizes, int n_in,
                              void* d_out, int out_size, void* d_ws, size_t ws_size,
                              hipStream_t stream) {
  const float* seq  = (const float*)d_in[0];
  const float* att  = (const float*)d_in[1];
  const float* Wh   = (const float*)d_in[2];
  const float* bh   = (const float*)d_in[3];
  const float* Wt   = (const float*)d_in[4];
  const float* bt   = (const float*)d_in[5];
  const float* Wb   = (const float*)d_in[6];
  const int* pos    = (const int*)d_in[7];
  const int* mask   = (const int*)d_in[8];
  const int* hts    = (const int*)d_in[9];
  float* out = (float*)d_out;

  float* ws = (float*)d_ws;
  // layout (float slots), total 14,842,880 f = 59.4 MB
  float*          eatt  = ws;                                   // 2,064,384 f
  unsigned short* htB   = (unsigned short*)(ws + 2064384);      // 4,194,304 us
  unsigned short* eembB = (unsigned short*)(ws + 4161536);      //   129,024 us
  unsigned short* seqTB = (unsigned short*)(ws + 4226048);      // 3,145,728 us
  unsigned short* WhtB  = (unsigned short*)(ws + 5798912);      // 2,359,296 us
  unsigned short* rsB   = (unsigned short*)(ws + 6978560);      // 3,145,728 us
  float*          hsb   = ws + 8551424;                         // 3,145,728 f
  float*          tsb   = ws + 11697152;                        // 3,145,728 f
  // aliases (valid by launch order):
  unsigned short* WpB   = (unsigned short*)eatt;   // 5,505,024 us <= eatt+htB span; written after k_rs_mfma
  unsigned short* hsTB  = (unsigned short*)seqTB;  // 3,145,728 us = seqTB span; written after k_rs_mfma

  k_eemb<<<dim3(EEE, NDOC), 256, 0, stream>>>(seq, pos, mask, eembB);
  k_eatt<<<dim3(HHH, EEE, NDOC), 256, 0, stream>>>(att, pos, mask, eatt);
  k_htatt<<<dim3(NDOC*PPP), 256, 0, stream>>>(eatt, hts, htB);
  k_packW<<<dim3(1152), 256, 0, stream>>>(Wh, Wt, WhtB);
  k_seqT<<<dim3(DDD/64, CCC/64, NDOC), 256, 0, stream>>>(seq, seqTB);
  k_rs_mfma<<<dim3(6, 32), 256, 0, stream>>>(htB, seqTB, rsB);
  k_prep_w<<<dim3(2688), 256, 0, stream>>>(Wb, WpB);
  k_heads_mfma<<<dim3(6, 32, 2), 256, 0, stream>>>(eembB, rsB, hts, WhtB, bh, bt, hsb, tsb);
  k_pack_hs<<<dim3(DDD/64, 4096/64), 256, 0, stream>>>(hsb, hsTB);
  k_zero<<<dim3(396), 256, 0, stream>>>(out);
  k_logits_mfma<<<dim3(24, 32), 128, 0, stream>>>(hsTB, tsb, WpB, out);
}

// Round 7
// 226.483 us; speedup vs baseline: 8.1431x; 1.2086x over previous
//
#include <hip/hip_runtime.h>
#include <hip/hip_bf16.h>
#include <hip/hip_fp16.h>
#include <math.h>

#define NDOC 4
#define CCC  1024
#define DDD  768
#define HHH  12
#define EEE  42
#define MMM  8
#define PPP  1024
#define NBQ  12
#define NK   99
#define NPAD 112

typedef __attribute__((ext_vector_type(8))) short short8v;
typedef __attribute__((ext_vector_type(8))) _Float16 half8;
typedef __attribute__((ext_vector_type(4))) float floatx4;

__device__ __forceinline__ unsigned short f32_to_bf16u(float f) {
  return __builtin_bit_cast(unsigned short, __float2bfloat16(f));
}
__device__ __forceinline__ unsigned short f32_to_f16u(float f) {
  return __builtin_bit_cast(unsigned short, __float2half(f));
}

// ---------------- K1: e_emb = logsumexp over valid mentions (bf16 out) -----
__global__ __launch_bounds__(256) void k_eemb(const float* __restrict__ seq,
    const int* __restrict__ pos, const int* __restrict__ mask,
    unsigned short* __restrict__ eembB) {
  int e = blockIdx.x, doc = blockIdx.y;
  int base = (doc*EEE + e)*MMM;
  int p[MMM], mk[MMM];
#pragma unroll
  for (int m = 0; m < MMM; ++m) { p[m] = pos[base+m] + 1; mk[m] = mask[base+m]; }
  for (int d0 = threadIdx.x; d0 < DDD; d0 += 256) {
    float v[MMM]; float mx = -INFINITY;
#pragma unroll
    for (int m = 0; m < MMM; ++m) {
      v[m] = seq[(doc*CCC + p[m])*DDD + d0];
      if (mk[m]) mx = fmaxf(mx, v[m]);
    }
    float s = 0.f;
#pragma unroll
    for (int m = 0; m < MMM; ++m) if (mk[m]) s += expf(v[m]-mx);
    eembB[(doc*EEE + e)*DDD + d0] = f32_to_bf16u(logf(s) + mx);
  }
}

// ---------------- K2: e_att (fp32) ----------------------------------------
__global__ __launch_bounds__(256) void k_eatt(const float* __restrict__ att,
    const int* __restrict__ pos, const int* __restrict__ mask,
    float* __restrict__ eatt) {
  int head = blockIdx.x, e = blockIdx.y, doc = blockIdx.z;
  int base = (doc*EEE + e)*MMM;
  int j = threadIdx.x * 4;
  float ax=0.f, ay=0.f, az=0.f, aw=0.f; float cnt = 0.f;
#pragma unroll
  for (int m = 0; m < MMM; ++m) {
    int mk = mask[base+m];
    cnt += (float)mk;
    if (mk) {
      int pp = pos[base+m] + 1;
      const float4 a = *(const float4*)&att[((size_t)(doc*HHH + head)*CCC + pp)*CCC + j];
      ax += a.x; ay += a.y; az += a.z; aw += a.w;
    }
  }
  float inv = 1.f / cnt;
  float4 o; o.x = ax*inv; o.y = ay*inv; o.z = az*inv; o.w = aw*inv;
  *(float4*)&eatt[((size_t)((doc*EEE + e)*HHH + head))*CCC + j] = o;
}

// ---------------- K3: ht_att -> bf16 out ----------------------------------
__global__ __launch_bounds__(256) void k_htatt(const float* __restrict__ eatt,
    const int* __restrict__ hts, unsigned short* __restrict__ htB) {
  int b = blockIdx.x; int doc = b >> 10; int r = b & 1023;
  int h0 = hts[(doc*PPP + r)*2 + 0];
  int t0 = hts[(doc*PPP + r)*2 + 1];
  const float* ea0 = &eatt[(size_t)((doc*EEE + h0)*HHH)*CCC];
  const float* ea1 = &eatt[(size_t)((doc*EEE + t0)*HHH)*CCC];
  int j = threadIdx.x * 4;
  float vx=0.f, vy=0.f, vz=0.f, vw=0.f;
#pragma unroll
  for (int hh = 0; hh < HHH; ++hh) {
    const float4 a  = *(const float4*)&ea0[hh*CCC + j];
    const float4 bq = *(const float4*)&ea1[hh*CCC + j];
    vx += a.x*bq.x; vy += a.y*bq.y; vz += a.z*bq.z; vw += a.w*bq.w;
  }
  const float inv12 = 1.f/12.f;
  vx *= inv12; vy *= inv12; vz *= inv12; vw *= inv12;
  float part = vx + vy + vz + vw;
  __shared__ float red[4];
  for (int off = 32; off > 0; off >>= 1) part += __shfl_down(part, off, 64);
  int lane = threadIdx.x & 63, wv = threadIdx.x >> 6;
  if (lane == 0) red[wv] = part;
  __syncthreads();
  if (threadIdx.x == 0) red[0] = red[0]+red[1]+red[2]+red[3];
  __syncthreads();
  float sc = 1.f / (red[0] + 1e-5f);
  unsigned short o[4];
  o[0] = f32_to_bf16u(vx*sc); o[1] = f32_to_bf16u(vy*sc);
  o[2] = f32_to_bf16u(vz*sc); o[3] = f32_to_bf16u(vw*sc);
  *(uint2*)&htB[((size_t)(doc*PPP + r))*CCC + j] = *(const uint2*)o;
}

// ---------------- K3b: pack Wh|Wt -> bf16 [2][768][1536] -------------------
__global__ __launch_bounds__(256) void k_packW(const float* __restrict__ Wh,
    const float* __restrict__ Wt, unsigned short* __restrict__ WB) {
  int gid = blockIdx.x*256 + threadIdx.x;
  int half = gid >= 147456;
  int loc = half ? gid - 147456 : gid;
  const float* src = (half ? Wt : Wh) + (size_t)loc*8;
  float4 v0 = *(const float4*)src;
  float4 v1 = *(const float4*)(src+4);
  unsigned short o[8];
  o[0]=f32_to_bf16u(v0.x); o[1]=f32_to_bf16u(v0.y); o[2]=f32_to_bf16u(v0.z); o[3]=f32_to_bf16u(v0.w);
  o[4]=f32_to_bf16u(v1.x); o[5]=f32_to_bf16u(v1.y); o[6]=f32_to_bf16u(v1.z); o[7]=f32_to_bf16u(v1.w);
  *(uint4*)&WB[(size_t)half*1179648 + (size_t)loc*8] = *(const uint4*)o;
}

// ---------------- K3c: seqT bf16 [doc][768][1024] (transpose) --------------
__global__ __launch_bounds__(256) void k_seqT(const float* __restrict__ seq,
    unsigned short* __restrict__ seqTB) {
  __shared__ float tl[64][65];
  int d0 = blockIdx.x * 64, c0 = blockIdx.y * 64, doc = blockIdx.z;
  int t = threadIdx.x;
#pragma unroll
  for (int rep = 0; rep < 4; ++rep) {
    int cr = rep*16 + (t >> 4);
    int d4 = (t & 15) * 4;
    float4 v = *(const float4*)&seq[((size_t)doc*CCC + c0 + cr)*DDD + d0 + d4];
    tl[cr][d4+0]=v.x; tl[cr][d4+1]=v.y; tl[cr][d4+2]=v.z; tl[cr][d4+3]=v.w;
  }
  __syncthreads();
#pragma unroll
  for (int rep = 0; rep < 4; ++rep) {
    int dr = rep*16 + (t >> 4);
    int c4 = (t & 15) * 4;
    unsigned short o[4];
#pragma unroll
    for (int kq = 0; kq < 4; ++kq)
      o[kq] = f32_to_bf16u(tl[c4+kq][dr]);
    *(uint2*)&seqTB[((size_t)doc*DDD + d0 + dr)*CCC + c0 + c4] = *(const uint2*)o;
  }
}

// ---------------- K4: rs = htatt @ seq  (bf16 MFMA, reg-staged LDS) --------
__global__ __launch_bounds__(256) void k_rs_mfma(
    const unsigned short* __restrict__ htB,    // [doc][1024][1024]
    const unsigned short* __restrict__ seqTB,  // [doc][768][1024]
    unsigned short* __restrict__ rsB) {        // [4096][768]
  __shared__ unsigned short A_l[4096];
  __shared__ unsigned short B_l[4096];
  const int n0 = blockIdx.x * 128;
  const int m0 = blockIdx.y * 128;
  const int doc = m0 >> 10;
  const int mloc = m0 & 1023;
  const int t = threadIdx.x;
  const int lane = t & 63;
  const int ln = lane & 15, q4 = lane >> 4;
  const int w = t >> 6;
  const int wr = w >> 1, wc = w & 1;

  const int r0 = t >> 2;
  const int koff = (t & 3) * 8;
  const unsigned short* srcA0 = htB + ((size_t)doc*CCC + mloc + r0)*CCC + koff;
  const unsigned short* srcA1 = htB + ((size_t)doc*CCC + mloc + r0 + 64)*CCC + koff;
  const unsigned short* srcB0 = seqTB + ((size_t)doc*DDD + n0 + r0)*CCC + koff;
  const unsigned short* srcB1 = seqTB + ((size_t)doc*DDD + n0 + r0 + 64)*CCC + koff;

  floatx4 acc[4][4];
#pragma unroll
  for (int i = 0; i < 4; ++i)
#pragma unroll
    for (int j = 0; j < 4; ++j) acc[i][j] = (floatx4){0.f,0.f,0.f,0.f};

  for (int k0 = 0; k0 < CCC; k0 += 32) {
    uint4 va0 = *(const uint4*)(srcA0 + k0);
    uint4 va1 = *(const uint4*)(srcA1 + k0);
    uint4 vb0 = *(const uint4*)(srcB0 + k0);
    uint4 vb1 = *(const uint4*)(srcB1 + k0);
    __syncthreads();
    *(uint4*)&A_l[(size_t)t*8]       = va0;
    *(uint4*)&A_l[(size_t)(t+256)*8] = va1;
    *(uint4*)&B_l[(size_t)t*8]       = vb0;
    *(uint4*)&B_l[(size_t)(t+256)*8] = vb1;
    __syncthreads();
    short8v a[4], b[4];
#pragma unroll
    for (int rt = 0; rt < 4; ++rt)
      a[rt] = *(const short8v*)&A_l[((wr*64 + rt*16 + ln)*4 + q4)*8];
#pragma unroll
    for (int nt = 0; nt < 4; ++nt)
      b[nt] = *(const short8v*)&B_l[((wc*64 + nt*16 + ln)*4 + q4)*8];
#pragma unroll
    for (int rt = 0; rt < 4; ++rt)
#pragma unroll
      for (int nt = 0; nt < 4; ++nt)
        acc[rt][nt] = __builtin_amdgcn_mfma_f32_16x16x32_bf16(a[rt], b[nt], acc[rt][nt], 0, 0, 0);
  }
#pragma unroll
  for (int rt = 0; rt < 4; ++rt)
#pragma unroll
    for (int nt = 0; nt < 4; ++nt) {
      int col = n0 + wc*64 + nt*16 + ln;
#pragma unroll
      for (int reg = 0; reg < 4; ++reg) {
        int row = m0 + wr*64 + rt*16 + q4*4 + reg;
        rsB[(size_t)row*DDD + col] = f32_to_bf16u(acc[rt][nt][reg]);
      }
    }
}

// ---------------- K5: heads GEMM (bf16 MFMA, gather-A, tanh epilogue) ------
__global__ __launch_bounds__(256) void k_heads_mfma(
    const unsigned short* __restrict__ eembB,  // [4*42][768]
    const unsigned short* __restrict__ rsB,    // [4096][768]
    const int* __restrict__ hts,
    const unsigned short* __restrict__ WB,     // [2][768][1536]
    const float* __restrict__ bh, const float* __restrict__ bt,
    float* __restrict__ hsb, float* __restrict__ tsb) {
  __shared__ unsigned short A_l[4096];
  __shared__ unsigned short B_l[4096];
  const int which = blockIdx.z;
  const int n0 = blockIdx.x * 128;
  const int m0 = blockIdx.y * 128;
  const int doc = m0 >> 10;
  const int t = threadIdx.x;
  const int lane = t & 63;
  const int ln = lane & 15, q4 = lane >> 4;
  const int w = t >> 6;
  const int wr = w >> 1, wc = w & 1;

  const int r0 = t >> 2;
  const int koff = (t & 3) * 8;
  const int rgA0 = m0 + r0, rgA1 = m0 + r0 + 64;
  const int idx0 = hts[rgA0*2 + which];
  const int idx1 = hts[rgA1*2 + which];
  const unsigned short* srcE0 = eembB + (size_t)(doc*EEE + idx0)*DDD + koff;
  const unsigned short* srcE1 = eembB + (size_t)(doc*EEE + idx1)*DDD + koff;
  const unsigned short* srcR0 = rsB + (size_t)rgA0*DDD + koff;
  const unsigned short* srcR1 = rsB + (size_t)rgA1*DDD + koff;
  const unsigned short* WBz = WB + (size_t)which*1179648;
  const unsigned short* srcW0 = WBz + (size_t)(n0 + r0)*1536 + koff;
  const unsigned short* srcW1 = WBz + (size_t)(n0 + r0 + 64)*1536 + koff;

  floatx4 acc[4][4];
#pragma unroll
  for (int i = 0; i < 4; ++i)
#pragma unroll
    for (int j = 0; j < 4; ++j) acc[i][j] = (floatx4){0.f,0.f,0.f,0.f};

  for (int k0 = 0; k0 < 1536; k0 += 32) {
    uint4 va0 = (k0 < DDD) ? *(const uint4*)(srcE0 + k0) : *(const uint4*)(srcR0 + (k0 - DDD));
    uint4 va1 = (k0 < DDD) ? *(const uint4*)(srcE1 + k0) : *(const uint4*)(srcR1 + (k0 - DDD));
    uint4 vb0 = *(const uint4*)(srcW0 + k0);
    uint4 vb1 = *(const uint4*)(srcW1 + k0);
    __syncthreads();
    *(uint4*)&A_l[(size_t)t*8]       = va0;
    *(uint4*)&A_l[(size_t)(t+256)*8] = va1;
    *(uint4*)&B_l[(size_t)t*8]       = vb0;
    *(uint4*)&B_l[(size_t)(t+256)*8] = vb1;
    __syncthreads();
    short8v a[4], b[4];
#pragma unroll
    for (int rt = 0; rt < 4; ++rt)
      a[rt] = *(const short8v*)&A_l[((wr*64 + rt*16 + ln)*4 + q4)*8];
#pragma unroll
    for (int nt = 0; nt < 4; ++nt)
      b[nt] = *(const short8v*)&B_l[((wc*64 + nt*16 + ln)*4 + q4)*8];
#pragma unroll
    for (int rt = 0; rt < 4; ++rt)
#pragma unroll
      for (int nt = 0; nt < 4; ++nt)
        acc[rt][nt] = __builtin_amdgcn_mfma_f32_16x16x32_bf16(a[rt], b[nt], acc[rt][nt], 0, 0, 0);
  }
  const float* bias = which ? bt : bh;
  float* outp = which ? tsb : hsb;
#pragma unroll
  for (int rt = 0; rt < 4; ++rt)
#pragma unroll
    for (int nt = 0; nt < 4; ++nt) {
      int col = n0 + wc*64 + nt*16 + ln;
      float bsv = bias[col];
#pragma unroll
      for (int reg = 0; reg < 4; ++reg) {
        int row = m0 + wr*64 + rt*16 + q4*4 + reg;
        outp[(size_t)row*DDD + col] = tanhf(acc[rt][nt][reg] + bsv);
      }
    }
}

// ------- K6a: pack Wb fp32 [99][49152] -> fp16 tiles Wp[ki][n(112)][j(64)] -
__global__ __launch_bounds__(256) void k_prep_w(const float* __restrict__ Wb,
    unsigned short* __restrict__ Wp) {
  int t = blockIdx.x*256 + threadIdx.x;
  int j = (t & 7) * 8;
  int n = (t >> 3) % NPAD;
  int ki = t / 896;
  unsigned short o[8];
  if (n < NK) {
    const float* src = &Wb[(size_t)n*49152 + ki*64 + j];
    float4 v0 = *(const float4*)src;
    float4 v1 = *(const float4*)(src+4);
    o[0]=f32_to_f16u(v0.x); o[1]=f32_to_f16u(v0.y); o[2]=f32_to_f16u(v0.z); o[3]=f32_to_f16u(v0.w);
    o[4]=f32_to_f16u(v1.x); o[5]=f32_to_f16u(v1.y); o[6]=f32_to_f16u(v1.z); o[7]=f32_to_f16u(v1.w);
  } else {
#pragma unroll
    for (int e=0;e<8;++e) o[e]=0;
  }
  *(uint4*)&Wp[(size_t)ki*7168 + n*64 + j] = *(const uint4*)o;
}

// ------- K6b: hsT_g[i][r] = fp16(hs[r][i]) ---------------------------------
__global__ __launch_bounds__(256) void k_pack_hs(const float* __restrict__ hs,
    unsigned short* __restrict__ hsT) {
  __shared__ float tl[64][65];
  int i0 = blockIdx.x * 64, r0 = blockIdx.y * 64;
  int t = threadIdx.x;
#pragma unroll
  for (int rep = 0; rep < 4; ++rep) {
    int r = rep*16 + (t >> 4);
    int c4 = (t & 15) * 4;
    float4 v = *(const float4*)&hs[(size_t)(r0 + r)*DDD + i0 + c4];
    tl[r][c4+0]=v.x; tl[r][c4+1]=v.y; tl[r][c4+2]=v.z; tl[r][c4+3]=v.w;
  }
  __syncthreads();
#pragma unroll
  for (int rep = 0; rep < 4; ++rep) {
    int i = rep*16 + (t >> 4);
    int r4 = (t & 15) * 4;
    unsigned short o[4];
#pragma unroll
    for (int kq = 0; kq < 4; ++kq)
      o[kq] = f32_to_f16u(tl[r4+kq][i]);
    *(uint2*)&hsT[(size_t)(i0 + i)*4096 + r0 + r4] = *(const uint2*)o;
  }
}

// ------- K6: logits partials via fp16 MFMA, A = outer(hs,ts) on the fly ----
// grid (24, 32), 256 thr (4 waves, each wave = 32 rows). Double-buffered W.
// P[slice][row][col(112)] fp16 partial sums; no atomics.
__global__ __launch_bounds__(256, 3) void k_logits_mfma(
    const unsigned short* __restrict__ hsT,   // [768][4096] fp16
    const float* __restrict__ tsb,            // [4096][768] fp32
    const unsigned short* __restrict__ Wp,    // [768 ki][112 n][64 j] fp16
    unsigned short* __restrict__ P) {         // [24][4096][112] fp16
  __shared__ unsigned short hsT_l[32*128];    // [ii][r] 8 KB
  __shared__ unsigned short Bt_l[2*NPAD*72];  // dbuf [n][j] pad 72, 32.25 KB
  const int slice = blockIdx.x;
  const int kbase = (slice >> 1)*64 + (slice & 1)*32;  // nb*64 + ih
  const int mtile = blockIdx.y;
  const int t = threadIdx.x;
  const int w = t >> 6;           // wave 0..3, owns rows w*32..w*32+31
  const int lane = t & 63;
  const int ln = lane & 15;
  const int q = lane >> 4;
  const int m0w = mtile*128 + w*32;

  // ---- stage hsT tile [32 ki][128 r] (512 x 16B chunks, 2 per thread) ----
#pragma unroll
  for (int rep = 0; rep < 2; ++rep) {
    int c16 = t + rep*256;
    int ii = c16 >> 4;
    int c8 = (c16 & 15) * 8;
    uint4 v = *(const uint4*)&hsT[(size_t)(kbase + ii)*4096 + mtile*128 + c8];
    *(uint4*)&hsT_l[ii*128 + c8] = v;
  }

  // ---- ts fragment rows -> fp16 pairs in registers ----
  __half2 tsr2[2][2][4];
#pragma unroll
  for (int rt = 0; rt < 2; ++rt) {
    int row = m0w + rt*16 + ln;
    int nb = kbase >> 6;
#pragma unroll
    for (int js = 0; js < 2; ++js) {
      const float* p = &tsb[(size_t)row*DDD + nb*64 + js*32 + q*8];
      float4 v0 = *(const float4*)p;
      float4 v1 = *(const float4*)(p+4);
      tsr2[rt][js][0] = __floats2half2_rn(v0.x, v0.y);
      tsr2[rt][js][1] = __floats2half2_rn(v0.z, v0.w);
      tsr2[rt][js][2] = __floats2half2_rn(v1.x, v1.y);
      tsr2[rt][js][3] = __floats2half2_rn(v1.z, v1.w);
    }
  }

  floatx4 acc[2][7];
#pragma unroll
  for (int rt = 0; rt < 2; ++rt)
#pragma unroll
    for (int nt = 0; nt < 7; ++nt)
      acc[rt][nt] = (floatx4){0.f,0.f,0.f,0.f};

  // ---- prologue: load + write buf0 ----
  uint4 wreg[4];
#pragma unroll
  for (int r = 0; r < 4; ++r) {
    int chunk = t + r*256;
    if (chunk < 896) wreg[r] = *(const uint4*)&Wp[(size_t)kbase*7168 + chunk*8];
  }
#pragma unroll
  for (int r = 0; r < 4; ++r) {
    int chunk = t + r*256;
    if (chunk < 896) {
      int n = chunk >> 3, j8 = (chunk & 7)*8;
      *(uint4*)&Bt_l[n*72 + j8] = wreg[r];
    }
  }
  __syncthreads();   // hsT_l + buf0 staged

  for (int ii = 0; ii < 32; ++ii) {
    const unsigned short* bufc = Bt_l + (ii & 1)*(NPAD*72);
    // issue next tile's loads early (latency hides under MFMA below)
    if (ii < 31) {
      int ki = kbase + ii + 1;
#pragma unroll
      for (int r = 0; r < 4; ++r) {
        int chunk = t + r*256;
        if (chunk < 896) wreg[r] = *(const uint4*)&Wp[(size_t)ki*7168 + chunk*8];
      }
    }
    // compute on current buffer
    __half2 hh[2];
#pragma unroll
    for (int rt = 0; rt < 2; ++rt) {
      unsigned short hb = hsT_l[ii*128 + w*32 + rt*16 + ln];
      hh[rt] = __half2half2(__ushort_as_half(hb));
    }
#pragma unroll
    for (int js = 0; js < 2; ++js) {
      half8 a[2];
#pragma unroll
      for (int rt = 0; rt < 2; ++rt) {
        uint4 au;
        au.x = __builtin_bit_cast(unsigned int, __hmul2(hh[rt], tsr2[rt][js][0]));
        au.y = __builtin_bit_cast(unsigned int, __hmul2(hh[rt], tsr2[rt][js][1]));
        au.z = __builtin_bit_cast(unsigned int, __hmul2(hh[rt], tsr2[rt][js][2]));
        au.w = __builtin_bit_cast(unsigned int, __hmul2(hh[rt], tsr2[rt][js][3]));
        a[rt] = __builtin_bit_cast(half8, au);
      }
#pragma unroll
      for (int nt = 0; nt < 7; ++nt) {
        half8 b = __builtin_bit_cast(half8,
            *(const short8v*)&bufc[(nt*16 + ln)*72 + js*32 + q*8]);
#pragma unroll
        for (int rt = 0; rt < 2; ++rt)
          acc[rt][nt] = __builtin_amdgcn_mfma_f32_16x16x32_f16(a[rt], b, acc[rt][nt], 0, 0, 0);
      }
    }
    if (ii < 31) {
      __syncthreads();   // all waves done reading buf[(ii+1)&1] (from ii-1)
#pragma unroll
      for (int r = 0; r < 4; ++r) {
        int chunk = t + r*256;
        if (chunk < 896) {
          int n = chunk >> 3, j8 = (chunk & 7)*8;
          *(uint4*)&Bt_l[((ii+1) & 1)*(NPAD*72) + n*72 + j8] = wreg[r];
        }
      }
      __syncthreads();   // next buffer staged
    }
  }

  // ---- epilogue: regular fp16 stores of this slice's partials ----
  unsigned short* Ps = P + (size_t)slice*(4096*NPAD);
#pragma unroll
  for (int nt = 0; nt < 7; ++nt) {
    int col = nt*16 + ln;
#pragma unroll
    for (int rt = 0; rt < 2; ++rt) {
#pragma unroll
      for (int reg = 0; reg < 4; ++reg) {
        int row = m0w + rt*16 + q*4 + reg;
        Ps[(size_t)row*NPAD + col] = f32_to_f16u(acc[rt][nt][reg]);
      }
    }
  }
}

// ------- K7: reduce 24 fp16 partial slices -> logits fp32 ------------------
__global__ __launch_bounds__(256) void k_logred(const unsigned short* __restrict__ P,
    float* __restrict__ out) {
  int idx = blockIdx.x*256 + threadIdx.x;    // 0 .. 4096*112-1
  int r = idx / NPAD;
  int c = idx % NPAD;
  if (c >= NK) return;
  float s = 0.f;
#pragma unroll
  for (int sl = 0; sl < 24; ++sl)
    s += __half2float(__ushort_as_half(P[(size_t)sl*(4096*NPAD) + idx]));
  out[(size_t)r*NK + c] = s;
}

extern "C" void kernel_launch(void* const* d_in, const int* in_sizes, int n_in,
                              void* d_out, int out_size, void* d_ws, size_t ws_size,
                              hipStream_t stream) {
  const float* seq  = (const float*)d_in[0];
  const float* att  = (const float*)d_in[1];
  const float* Wh   = (const float*)d_in[2];
  const float* bh   = (const float*)d_in[3];
  const float* Wt   = (const float*)d_in[4];
  const float* bt   = (const float*)d_in[5];
  const float* Wb   = (const float*)d_in[6];
  const int* pos    = (const int*)d_in[7];
  const int* mask   = (const int*)d_in[8];
  const int* hts    = (const int*)d_in[9];
  float* out = (float*)d_out;

  float* ws = (float*)d_ws;
  // layout (float slots), total 14,842,880 f = 59.4 MB
  float*          eatt  = ws;                                   // 2,064,384 f
  unsigned short* htB   = (unsigned short*)(ws + 2064384);      // 4,194,304 us
  unsigned short* eembB = (unsigned short*)(ws + 4161536);      //   129,024 us
  unsigned short* seqTB = (unsigned short*)(ws + 4226048);      // 3,145,728 us
  unsigned short* WhtB  = (unsigned short*)(ws + 5798912);      // 2,359,296 us
  unsigned short* rsB   = (unsigned short*)(ws + 6978560);      // 3,145,728 us
  float*          hsb   = ws + 8551424;                         // 3,145,728 f
  float*          tsb   = ws + 11697152;                        // 3,145,728 f
  // aliases (valid by launch order):
  unsigned short* WpB   = (unsigned short*)eatt;   // 5,505,024 us; written after k_rs_mfma
  unsigned short* hsTB  = (unsigned short*)seqTB;  // 3,145,728 us; written after k_rs_mfma
  unsigned short* Pp    = (unsigned short*)(ws + 5798912);
  // Pp: 24*4096*112 = 11,010,048 us = 5,505,024 f -> spans 5798912..11303936
  // (over WhtB+rsB+hsb, all dead after k_heads_mfma/k_pack_hs; tsb untouched)

  k_eemb<<<dim3(EEE, NDOC), 256, 0, stream>>>(seq, pos, mask, eembB);
  k_eatt<<<dim3(HHH, EEE, NDOC), 256, 0, stream>>>(att, pos, mask, eatt);
  k_htatt<<<dim3(NDOC*PPP), 256, 0, stream>>>(eatt, hts, htB);
  k_packW<<<dim3(1152), 256, 0, stream>>>(Wh, Wt, WhtB);
  k_seqT<<<dim3(DDD/64, CCC/64, NDOC), 256, 0, stream>>>(seq, seqTB);
  k_rs_mfma<<<dim3(6, 32), 256, 0, stream>>>(htB, seqTB, rsB);
  k_prep_w<<<dim3(2688), 256, 0, stream>>>(Wb, WpB);
  k_heads_mfma<<<dim3(6, 32, 2), 256, 0, stream>>>(eembB, rsB, hts, WhtB, bh, bt, hsb, tsb);
  k_pack_hs<<<dim3(DDD/64, 4096/64), 256, 0, stream>>>(hsb, hsTB);
  k_logits_mfma<<<dim3(24, 32), 256, 0, stream>>>(hsTB, tsb, WpB, Pp);
  k_logred<<<dim3(4096*NPAD/256), 256, 0, stream>>>(Pp, out);
}

// Round 8
// 221.821 us; speedup vs baseline: 8.3142x; 1.0210x over previous
//
#include <hip/hip_runtime.h>
#include <hip/hip_bf16.h>
#include <hip/hip_fp16.h>
#include <math.h>

#define NDOC 4
#define CCC  1024
#define DDD  768
#define HHH  12
#define EEE  42
#define MMM  8
#define PPP  1024
#define NBQ  12
#define NK   99
#define NPAD 112

typedef __attribute__((ext_vector_type(8))) short short8v;
typedef __attribute__((ext_vector_type(8))) _Float16 half8;
typedef __attribute__((ext_vector_type(4))) float floatx4;

__device__ __forceinline__ unsigned short f32_to_bf16u(float f) {
  return __builtin_bit_cast(unsigned short, __float2bfloat16(f));
}
__device__ __forceinline__ unsigned short f32_to_f16u(float f) {
  return __builtin_bit_cast(unsigned short, __float2half(f));
}

// ---------------- K1: e_emb = logsumexp over valid mentions (bf16 out) -----
__global__ __launch_bounds__(256) void k_eemb(const float* __restrict__ seq,
    const int* __restrict__ pos, const int* __restrict__ mask,
    unsigned short* __restrict__ eembB) {
  int e = blockIdx.x, doc = blockIdx.y;
  int base = (doc*EEE + e)*MMM;
  int p[MMM], mk[MMM];
#pragma unroll
  for (int m = 0; m < MMM; ++m) { p[m] = pos[base+m] + 1; mk[m] = mask[base+m]; }
  for (int d0 = threadIdx.x; d0 < DDD; d0 += 256) {
    float v[MMM]; float mx = -INFINITY;
#pragma unroll
    for (int m = 0; m < MMM; ++m) {
      v[m] = seq[(doc*CCC + p[m])*DDD + d0];
      if (mk[m]) mx = fmaxf(mx, v[m]);
    }
    float s = 0.f;
#pragma unroll
    for (int m = 0; m < MMM; ++m) if (mk[m]) s += expf(v[m]-mx);
    eembB[(doc*EEE + e)*DDD + d0] = f32_to_bf16u(logf(s) + mx);
  }
}

// ---------------- K2: e_att (fp32) ----------------------------------------
__global__ __launch_bounds__(256) void k_eatt(const float* __restrict__ att,
    const int* __restrict__ pos, const int* __restrict__ mask,
    float* __restrict__ eatt) {
  int head = blockIdx.x, e = blockIdx.y, doc = blockIdx.z;
  int base = (doc*EEE + e)*MMM;
  int j = threadIdx.x * 4;
  float ax=0.f, ay=0.f, az=0.f, aw=0.f; float cnt = 0.f;
#pragma unroll
  for (int m = 0; m < MMM; ++m) {
    int mk = mask[base+m];
    cnt += (float)mk;
    if (mk) {
      int pp = pos[base+m] + 1;
      const float4 a = *(const float4*)&att[((size_t)(doc*HHH + head)*CCC + pp)*CCC + j];
      ax += a.x; ay += a.y; az += a.z; aw += a.w;
    }
  }
  float inv = 1.f / cnt;
  float4 o; o.x = ax*inv; o.y = ay*inv; o.z = az*inv; o.w = aw*inv;
  *(float4*)&eatt[((size_t)((doc*EEE + e)*HHH + head))*CCC + j] = o;
}

// ---------------- K3: ht_att -> bf16 out ----------------------------------
__global__ __launch_bounds__(256) void k_htatt(const float* __restrict__ eatt,
    const int* __restrict__ hts, unsigned short* __restrict__ htB) {
  int b = blockIdx.x; int doc = b >> 10; int r = b & 1023;
  int h0 = hts[(doc*PPP + r)*2 + 0];
  int t0 = hts[(doc*PPP + r)*2 + 1];
  const float* ea0 = &eatt[(size_t)((doc*EEE + h0)*HHH)*CCC];
  const float* ea1 = &eatt[(size_t)((doc*EEE + t0)*HHH)*CCC];
  int j = threadIdx.x * 4;
  float vx=0.f, vy=0.f, vz=0.f, vw=0.f;
#pragma unroll
  for (int hh = 0; hh < HHH; ++hh) {
    const float4 a  = *(const float4*)&ea0[hh*CCC + j];
    const float4 bq = *(const float4*)&ea1[hh*CCC + j];
    vx += a.x*bq.x; vy += a.y*bq.y; vz += a.z*bq.z; vw += a.w*bq.w;
  }
  const float inv12 = 1.f/12.f;
  vx *= inv12; vy *= inv12; vz *= inv12; vw *= inv12;
  float part = vx + vy + vz + vw;
  __shared__ float red[4];
  for (int off = 32; off > 0; off >>= 1) part += __shfl_down(part, off, 64);
  int lane = threadIdx.x & 63, wv = threadIdx.x >> 6;
  if (lane == 0) red[wv] = part;
  __syncthreads();
  if (threadIdx.x == 0) red[0] = red[0]+red[1]+red[2]+red[3];
  __syncthreads();
  float sc = 1.f / (red[0] + 1e-5f);
  unsigned short o[4];
  o[0] = f32_to_bf16u(vx*sc); o[1] = f32_to_bf16u(vy*sc);
  o[2] = f32_to_bf16u(vz*sc); o[3] = f32_to_bf16u(vw*sc);
  *(uint2*)&htB[((size_t)(doc*PPP + r))*CCC + j] = *(const uint2*)o;
}

// ---------------- K3b: pack Wh|Wt -> bf16 [2][768][1536] -------------------
__global__ __launch_bounds__(256) void k_packW(const float* __restrict__ Wh,
    const float* __restrict__ Wt, unsigned short* __restrict__ WB) {
  int gid = blockIdx.x*256 + threadIdx.x;
  int half = gid >= 147456;
  int loc = half ? gid - 147456 : gid;
  const float* src = (half ? Wt : Wh) + (size_t)loc*8;
  float4 v0 = *(const float4*)src;
  float4 v1 = *(const float4*)(src+4);
  unsigned short o[8];
  o[0]=f32_to_bf16u(v0.x); o[1]=f32_to_bf16u(v0.y); o[2]=f32_to_bf16u(v0.z); o[3]=f32_to_bf16u(v0.w);
  o[4]=f32_to_bf16u(v1.x); o[5]=f32_to_bf16u(v1.y); o[6]=f32_to_bf16u(v1.z); o[7]=f32_to_bf16u(v1.w);
  *(uint4*)&WB[(size_t)half*1179648 + (size_t)loc*8] = *(const uint4*)o;
}

// ---------------- K3c: seqT bf16 [doc][768][1024] (transpose) --------------
__global__ __launch_bounds__(256) void k_seqT(const float* __restrict__ seq,
    unsigned short* __restrict__ seqTB) {
  __shared__ float tl[64][65];
  int d0 = blockIdx.x * 64, c0 = blockIdx.y * 64, doc = blockIdx.z;
  int t = threadIdx.x;
#pragma unroll
  for (int rep = 0; rep < 4; ++rep) {
    int cr = rep*16 + (t >> 4);
    int d4 = (t & 15) * 4;
    float4 v = *(const float4*)&seq[((size_t)doc*CCC + c0 + cr)*DDD + d0 + d4];
    tl[cr][d4+0]=v.x; tl[cr][d4+1]=v.y; tl[cr][d4+2]=v.z; tl[cr][d4+3]=v.w;
  }
  __syncthreads();
#pragma unroll
  for (int rep = 0; rep < 4; ++rep) {
    int dr = rep*16 + (t >> 4);
    int c4 = (t & 15) * 4;
    unsigned short o[4];
#pragma unroll
    for (int kq = 0; kq < 4; ++kq)
      o[kq] = f32_to_bf16u(tl[c4+kq][dr]);
    *(uint2*)&seqTB[((size_t)doc*DDD + d0 + dr)*CCC + c0 + c4] = *(const uint2*)o;
  }
}

// ---------------- K4: rs = htatt @ seq  (bf16 MFMA, reg-staged LDS) --------
__global__ __launch_bounds__(256) void k_rs_mfma(
    const unsigned short* __restrict__ htB,    // [doc][1024][1024]
    const unsigned short* __restrict__ seqTB,  // [doc][768][1024]
    unsigned short* __restrict__ rsB) {        // [4096][768]
  __shared__ unsigned short A_l[4096];
  __shared__ unsigned short B_l[4096];
  const int n0 = blockIdx.x * 128;
  const int m0 = blockIdx.y * 128;
  const int doc = m0 >> 10;
  const int mloc = m0 & 1023;
  const int t = threadIdx.x;
  const int lane = t & 63;
  const int ln = lane & 15, q4 = lane >> 4;
  const int w = t >> 6;
  const int wr = w >> 1, wc = w & 1;

  const int r0 = t >> 2;
  const int koff = (t & 3) * 8;
  const unsigned short* srcA0 = htB + ((size_t)doc*CCC + mloc + r0)*CCC + koff;
  const unsigned short* srcA1 = htB + ((size_t)doc*CCC + mloc + r0 + 64)*CCC + koff;
  const unsigned short* srcB0 = seqTB + ((size_t)doc*DDD + n0 + r0)*CCC + koff;
  const unsigned short* srcB1 = seqTB + ((size_t)doc*DDD + n0 + r0 + 64)*CCC + koff;

  floatx4 acc[4][4];
#pragma unroll
  for (int i = 0; i < 4; ++i)
#pragma unroll
    for (int j = 0; j < 4; ++j) acc[i][j] = (floatx4){0.f,0.f,0.f,0.f};

  for (int k0 = 0; k0 < CCC; k0 += 32) {
    uint4 va0 = *(const uint4*)(srcA0 + k0);
    uint4 va1 = *(const uint4*)(srcA1 + k0);
    uint4 vb0 = *(const uint4*)(srcB0 + k0);
    uint4 vb1 = *(const uint4*)(srcB1 + k0);
    __syncthreads();
    *(uint4*)&A_l[(size_t)t*8]       = va0;
    *(uint4*)&A_l[(size_t)(t+256)*8] = va1;
    *(uint4*)&B_l[(size_t)t*8]       = vb0;
    *(uint4*)&B_l[(size_t)(t+256)*8] = vb1;
    __syncthreads();
    short8v a[4], b[4];
#pragma unroll
    for (int rt = 0; rt < 4; ++rt)
      a[rt] = *(const short8v*)&A_l[((wr*64 + rt*16 + ln)*4 + q4)*8];
#pragma unroll
    for (int nt = 0; nt < 4; ++nt)
      b[nt] = *(const short8v*)&B_l[((wc*64 + nt*16 + ln)*4 + q4)*8];
#pragma unroll
    for (int rt = 0; rt < 4; ++rt)
#pragma unroll
      for (int nt = 0; nt < 4; ++nt)
        acc[rt][nt] = __builtin_amdgcn_mfma_f32_16x16x32_bf16(a[rt], b[nt], acc[rt][nt], 0, 0, 0);
  }
#pragma unroll
  for (int rt = 0; rt < 4; ++rt)
#pragma unroll
    for (int nt = 0; nt < 4; ++nt) {
      int col = n0 + wc*64 + nt*16 + ln;
#pragma unroll
      for (int reg = 0; reg < 4; ++reg) {
        int row = m0 + wr*64 + rt*16 + q4*4 + reg;
        rsB[(size_t)row*DDD + col] = f32_to_bf16u(acc[rt][nt][reg]);
      }
    }
}

// ---------------- K5: heads GEMM (bf16 MFMA, gather-A, tanh epilogue) ------
__global__ __launch_bounds__(256) void k_heads_mfma(
    const unsigned short* __restrict__ eembB,  // [4*42][768]
    const unsigned short* __restrict__ rsB,    // [4096][768]
    const int* __restrict__ hts,
    const unsigned short* __restrict__ WB,     // [2][768][1536]
    const float* __restrict__ bh, const float* __restrict__ bt,
    float* __restrict__ hsb, float* __restrict__ tsb) {
  __shared__ unsigned short A_l[4096];
  __shared__ unsigned short B_l[4096];
  const int which = blockIdx.z;
  const int n0 = blockIdx.x * 128;
  const int m0 = blockIdx.y * 128;
  const int doc = m0 >> 10;
  const int t = threadIdx.x;
  const int lane = t & 63;
  const int ln = lane & 15, q4 = lane >> 4;
  const int w = t >> 6;
  const int wr = w >> 1, wc = w & 1;

  const int r0 = t >> 2;
  const int koff = (t & 3) * 8;
  const int rgA0 = m0 + r0, rgA1 = m0 + r0 + 64;
  const int idx0 = hts[rgA0*2 + which];
  const int idx1 = hts[rgA1*2 + which];
  const unsigned short* srcE0 = eembB + (size_t)(doc*EEE + idx0)*DDD + koff;
  const unsigned short* srcE1 = eembB + (size_t)(doc*EEE + idx1)*DDD + koff;
  const unsigned short* srcR0 = rsB + (size_t)rgA0*DDD + koff;
  const unsigned short* srcR1 = rsB + (size_t)rgA1*DDD + koff;
  const unsigned short* WBz = WB + (size_t)which*1179648;
  const unsigned short* srcW0 = WBz + (size_t)(n0 + r0)*1536 + koff;
  const unsigned short* srcW1 = WBz + (size_t)(n0 + r0 + 64)*1536 + koff;

  floatx4 acc[4][4];
#pragma unroll
  for (int i = 0; i < 4; ++i)
#pragma unroll
    for (int j = 0; j < 4; ++j) acc[i][j] = (floatx4){0.f,0.f,0.f,0.f};

  for (int k0 = 0; k0 < 1536; k0 += 32) {
    uint4 va0 = (k0 < DDD) ? *(const uint4*)(srcE0 + k0) : *(const uint4*)(srcR0 + (k0 - DDD));
    uint4 va1 = (k0 < DDD) ? *(const uint4*)(srcE1 + k0) : *(const uint4*)(srcR1 + (k0 - DDD));
    uint4 vb0 = *(const uint4*)(srcW0 + k0);
    uint4 vb1 = *(const uint4*)(srcW1 + k0);
    __syncthreads();
    *(uint4*)&A_l[(size_t)t*8]       = va0;
    *(uint4*)&A_l[(size_t)(t+256)*8] = va1;
    *(uint4*)&B_l[(size_t)t*8]       = vb0;
    *(uint4*)&B_l[(size_t)(t+256)*8] = vb1;
    __syncthreads();
    short8v a[4], b[4];
#pragma unroll
    for (int rt = 0; rt < 4; ++rt)
      a[rt] = *(const short8v*)&A_l[((wr*64 + rt*16 + ln)*4 + q4)*8];
#pragma unroll
    for (int nt = 0; nt < 4; ++nt)
      b[nt] = *(const short8v*)&B_l[((wc*64 + nt*16 + ln)*4 + q4)*8];
#pragma unroll
    for (int rt = 0; rt < 4; ++rt)
#pragma unroll
      for (int nt = 0; nt < 4; ++nt)
        acc[rt][nt] = __builtin_amdgcn_mfma_f32_16x16x32_bf16(a[rt], b[nt], acc[rt][nt], 0, 0, 0);
  }
  const float* bias = which ? bt : bh;
  float* outp = which ? tsb : hsb;
#pragma unroll
  for (int rt = 0; rt < 4; ++rt)
#pragma unroll
    for (int nt = 0; nt < 4; ++nt) {
      int col = n0 + wc*64 + nt*16 + ln;
      float bsv = bias[col];
#pragma unroll
      for (int reg = 0; reg < 4; ++reg) {
        int row = m0 + wr*64 + rt*16 + q4*4 + reg;
        outp[(size_t)row*DDD + col] = tanhf(acc[rt][nt][reg] + bsv);
      }
    }
}

// ------- K6a: pack Wb fp32 -> fp16, fragment-major global layout -----------
// element (ki, n, j): js=j>>5, q=(j>>3)&3, e=j&7, nt=n>>4, lnn=n&15
// chunk c = ((js*7+nt)*4+q)*16 + lnn ; Wp[ki*7168 + c*8 + e]
__global__ __launch_bounds__(256) void k_prep_w(const float* __restrict__ Wb,
    unsigned short* __restrict__ Wp) {
  int t = blockIdx.x*256 + threadIdx.x;
  int j8 = (t & 7) * 8;
  int n = (t >> 3) % NPAD;
  int ki = t / 896;
  unsigned short o[8];
  if (n < NK) {
    const float* src = &Wb[(size_t)n*49152 + ki*64 + j8];
    float4 v0 = *(const float4*)src;
    float4 v1 = *(const float4*)(src+4);
    o[0]=f32_to_f16u(v0.x); o[1]=f32_to_f16u(v0.y); o[2]=f32_to_f16u(v0.z); o[3]=f32_to_f16u(v0.w);
    o[4]=f32_to_f16u(v1.x); o[5]=f32_to_f16u(v1.y); o[6]=f32_to_f16u(v1.z); o[7]=f32_to_f16u(v1.w);
  } else {
#pragma unroll
    for (int e=0;e<8;++e) o[e]=0;
  }
  int js = (t & 7) >> 2, q = t & 3;
  int nt = n >> 4, lnn = n & 15;
  int c = ((js*7 + nt)*4 + q)*16 + lnn;
  *(uint4*)&Wp[(size_t)ki*7168 + c*8] = *(const uint4*)o;
}

// ------- K6b: hsT_g[i][r] = fp16(hs[r][i]) ---------------------------------
__global__ __launch_bounds__(256) void k_pack_hs(const float* __restrict__ hs,
    unsigned short* __restrict__ hsT) {
  __shared__ float tl[64][65];
  int i0 = blockIdx.x * 64, r0 = blockIdx.y * 64;
  int t = threadIdx.x;
#pragma unroll
  for (int rep = 0; rep < 4; ++rep) {
    int r = rep*16 + (t >> 4);
    int c4 = (t & 15) * 4;
    float4 v = *(const float4*)&hs[(size_t)(r0 + r)*DDD + i0 + c4];
    tl[r][c4+0]=v.x; tl[r][c4+1]=v.y; tl[r][c4+2]=v.z; tl[r][c4+3]=v.w;
  }
  __syncthreads();
#pragma unroll
  for (int rep = 0; rep < 4; ++rep) {
    int i = rep*16 + (t >> 4);
    int r4 = (t & 15) * 4;
    unsigned short o[4];
#pragma unroll
    for (int kq = 0; kq < 4; ++kq)
      o[kq] = f32_to_f16u(tl[r4+kq][i]);
    *(uint2*)&hsT[(size_t)(i0 + i)*4096 + r0 + r4] = *(const uint2*)o;
  }
}

// ------- K6: logits partials via fp16 MFMA, A = outer(hs,ts) on the fly ----
// grid (24, 32), 128 thr (2 waves, each wave = 64 rows, rt=4).
// B LDS layout fragment-major: chunk c -> lds[c*8 shorts]; B-frag read for
// (js,nt) = lds[((js*7+nt)*4)*128 + lane*8] : lane-linear, conflict-free.
__global__ __launch_bounds__(128, 2) void k_logits_mfma(
    const unsigned short* __restrict__ hsT,   // [768][4096] fp16
    const float* __restrict__ tsb,            // [4096][768] fp32
    const unsigned short* __restrict__ Wp,    // [768 ki][896 c][8] fp16
    unsigned short* __restrict__ P) {         // [24][4096][112] fp16
  __shared__ unsigned short hsT_l[32*128];    // [ii][r] 8 KB
  __shared__ unsigned short Bt_l[2*7168];     // dbuf, fragment-major, 28 KB
  const int slice = blockIdx.x;
  const int kbase = (slice >> 1)*64 + (slice & 1)*32;
  const int mtile = blockIdx.y;
  const int t = threadIdx.x;
  const int w = t >> 6;           // wave 0/1, owns rows w*64..w*64+63
  const int lane = t & 63;
  const int ln = lane & 15;
  const int q = lane >> 4;
  const int m0w = mtile*128 + w*64;

  // ---- stage hsT tile [32 ki][128 r] (512 x 16B chunks, 4 per thread) ----
#pragma unroll
  for (int rep = 0; rep < 4; ++rep) {
    int c16 = t + rep*128;
    int ii = c16 >> 4;
    int c8 = (c16 & 15) * 8;
    uint4 v = *(const uint4*)&hsT[(size_t)(kbase + ii)*4096 + mtile*128 + c8];
    *(uint4*)&hsT_l[ii*128 + c8] = v;
  }

  // ---- ts fragment rows -> fp16 pairs in registers ----
  __half2 tsr2[4][2][4];
  {
    int nb = kbase >> 6;
#pragma unroll
    for (int rt = 0; rt < 4; ++rt) {
      int row = m0w + rt*16 + ln;
#pragma unroll
      for (int js = 0; js < 2; ++js) {
        const float* p = &tsb[(size_t)row*DDD + nb*64 + js*32 + q*8];
        float4 v0 = *(const float4*)p;
        float4 v1 = *(const float4*)(p+4);
        tsr2[rt][js][0] = __floats2half2_rn(v0.x, v0.y);
        tsr2[rt][js][1] = __floats2half2_rn(v0.z, v0.w);
        tsr2[rt][js][2] = __floats2half2_rn(v1.x, v1.y);
        tsr2[rt][js][3] = __floats2half2_rn(v1.z, v1.w);
      }
    }
  }

  floatx4 acc[4][7];
#pragma unroll
  for (int rt = 0; rt < 4; ++rt)
#pragma unroll
    for (int nt = 0; nt < 7; ++nt)
      acc[rt][nt] = (floatx4){0.f,0.f,0.f,0.f};

  // ---- prologue: stage buf0 (896 chunks / 128 thr = 7 each, linear) ----
  uint4 wreg[7];
#pragma unroll
  for (int r = 0; r < 7; ++r)
    wreg[r] = *(const uint4*)&Wp[(size_t)kbase*7168 + (t + r*128)*8];
#pragma unroll
  for (int r = 0; r < 7; ++r)
    *(uint4*)&Bt_l[(t + r*128)*8] = wreg[r];
  __syncthreads();   // hsT_l + buf0 staged

  for (int ii = 0; ii < 32; ++ii) {
    const unsigned short* bufc = Bt_l + (ii & 1)*7168;
    // issue next tile's loads early (hide under MFMA below)
    if (ii < 31) {
      int ki = kbase + ii + 1;
#pragma unroll
      for (int r = 0; r < 7; ++r)
        wreg[r] = *(const uint4*)&Wp[(size_t)ki*7168 + (t + r*128)*8];
    }
    __half2 hh[4];
#pragma unroll
    for (int rt = 0; rt < 4; ++rt) {
      unsigned short hb = hsT_l[ii*128 + w*64 + rt*16 + ln];
      hh[rt] = __half2half2(__ushort_as_half(hb));
    }
#pragma unroll
    for (int js = 0; js < 2; ++js) {
      half8 a[4];
#pragma unroll
      for (int rt = 0; rt < 4; ++rt) {
        uint4 au;
        au.x = __builtin_bit_cast(unsigned int, __hmul2(hh[rt], tsr2[rt][js][0]));
        au.y = __builtin_bit_cast(unsigned int, __hmul2(hh[rt], tsr2[rt][js][1]));
        au.z = __builtin_bit_cast(unsigned int, __hmul2(hh[rt], tsr2[rt][js][2]));
        au.w = __builtin_bit_cast(unsigned int, __hmul2(hh[rt], tsr2[rt][js][3]));
        a[rt] = __builtin_bit_cast(half8, au);
      }
#pragma unroll
      for (int nt = 0; nt < 7; ++nt) {
        half8 b = __builtin_bit_cast(half8,
            *(const short8v*)&bufc[((js*7 + nt)*4)*128 + lane*8]);
#pragma unroll
        for (int rt = 0; rt < 4; ++rt)
          acc[rt][nt] = __builtin_amdgcn_mfma_f32_16x16x32_f16(a[rt], b, acc[rt][nt], 0, 0, 0);
      }
    }
    if (ii < 31) {
      __syncthreads();   // all waves done reading buf[(ii+1)&1]
#pragma unroll
      for (int r = 0; r < 7; ++r)
        *(uint4*)&Bt_l[((ii+1) & 1)*7168 + (t + r*128)*8] = wreg[r];
      __syncthreads();   // next buffer staged
    }
  }

  // ---- epilogue: regular fp16 stores of this slice's partials ----
  unsigned short* Ps = P + (size_t)slice*(4096*NPAD);
#pragma unroll
  for (int nt = 0; nt < 7; ++nt) {
    int col = nt*16 + ln;
#pragma unroll
    for (int rt = 0; rt < 4; ++rt) {
#pragma unroll
      for (int reg = 0; reg < 4; ++reg) {
        int row = m0w + rt*16 + q*4 + reg;
        Ps[(size_t)row*NPAD + col] = f32_to_f16u(acc[rt][nt][reg]);
      }
    }
  }
}

// ------- K7: reduce 24 fp16 partial slices -> logits fp32 ------------------
__global__ __launch_bounds__(256) void k_logred(const unsigned short* __restrict__ P,
    float* __restrict__ out) {
  int idx = blockIdx.x*256 + threadIdx.x;    // 0 .. 4096*112-1
  int r = idx / NPAD;
  int c = idx % NPAD;
  if (c >= NK) return;
  float s = 0.f;
#pragma unroll
  for (int sl = 0; sl < 24; ++sl)
    s += __half2float(__ushort_as_half(P[(size_t)sl*(4096*NPAD) + idx]));
  out[(size_t)r*NK + c] = s;
}

extern "C" void kernel_launch(void* const* d_in, const int* in_sizes, int n_in,
                              void* d_out, int out_size, void* d_ws, size_t ws_size,
                              hipStream_t stream) {
  const float* seq  = (const float*)d_in[0];
  const float* att  = (const float*)d_in[1];
  const float* Wh   = (const float*)d_in[2];
  const float* bh   = (const float*)d_in[3];
  const float* Wt   = (const float*)d_in[4];
  const float* bt   = (const float*)d_in[5];
  const float* Wb   = (const float*)d_in[6];
  const int* pos    = (const int*)d_in[7];
  const int* mask   = (const int*)d_in[8];
  const int* hts    = (const int*)d_in[9];
  float* out = (float*)d_out;

  float* ws = (float*)d_ws;
  // layout (float slots), total 14,842,880 f = 59.4 MB
  float*          eatt  = ws;                                   // 2,064,384 f
  unsigned short* htB   = (unsigned short*)(ws + 2064384);      // 4,194,304 us
  unsigned short* eembB = (unsigned short*)(ws + 4161536);      //   129,024 us
  unsigned short* seqTB = (unsigned short*)(ws + 4226048);      // 3,145,728 us
  unsigned short* WhtB  = (unsigned short*)(ws + 5798912);      // 2,359,296 us
  unsigned short* rsB   = (unsigned short*)(ws + 6978560);      // 3,145,728 us
  float*          hsb   = ws + 8551424;                         // 3,145,728 f
  float*          tsb   = ws + 11697152;                        // 3,145,728 f
  // aliases (valid by launch order):
  unsigned short* WpB   = (unsigned short*)eatt;   // 5,505,024 us; written after k_rs_mfma
  unsigned short* hsTB  = (unsigned short*)seqTB;  // 3,145,728 us; written after k_rs_mfma
  unsigned short* Pp    = (unsigned short*)(ws + 5798912);
  // Pp: 24*4096*112 = 11,010,048 us -> spans WhtB+rsB+hsb (dead by then); tsb untouched

  k_eemb<<<dim3(EEE, NDOC), 256, 0, stream>>>(seq, pos, mask, eembB);
  k_eatt<<<dim3(HHH, EEE, NDOC), 256, 0, stream>>>(att, pos, mask, eatt);
  k_htatt<<<dim3(NDOC*PPP), 256, 0, stream>>>(eatt, hts, htB);
  k_packW<<<dim3(1152), 256, 0, stream>>>(Wh, Wt, WhtB);
  k_seqT<<<dim3(DDD/64, CCC/64, NDOC), 256, 0, stream>>>(seq, seqTB);
  k_rs_mfma<<<dim3(6, 32), 256, 0, stream>>>(htB, seqTB, rsB);
  k_prep_w<<<dim3(2688), 256, 0, stream>>>(Wb, WpB);
  k_heads_mfma<<<dim3(6, 32, 2), 256, 0, stream>>>(eembB, rsB, hts, WhtB, bh, bt, hsb, tsb);
  k_pack_hs<<<dim3(DDD/64, 4096/64), 256, 0, stream>>>(hsb, hsTB);
  k_logits_mfma<<<dim3(24, 32), 128, 0, stream>>>(hsTB, tsb, WpB, Pp);
  k_logred<<<dim3(4096*NPAD/256), 256, 0, stream>>>(Pp, out);
}